// Round 11
// baseline (261.157 us; speedup 1.0000x reference)
//
#include <hip/hip_runtime.h>

typedef unsigned short u16;
typedef __attribute__((ext_vector_type(8))) short  short8;
typedef __attribute__((ext_vector_type(8))) __bf16 bf16x8;
typedef __attribute__((ext_vector_type(4))) float  f32x4;

#define DEV __device__ __forceinline__

// B=8, N=1025, D=1024, H=16, Dh=64
#define BATCH 8
#define SEQ   1025
#define DMODEL 1024
#define NHEAD 16
#define DH    64
#define MROWS (BATCH*SEQ)      // 8200
#define VPAD  1152             // key padding for VT
#define KROWS 1088             // padded K row stride (17*64)

DEV float bf2f(u16 u) { union { unsigned int i; float f; } v; v.i = ((unsigned int)u) << 16; return v.f; }
DEV u16 f2bf(float f) {
  union { float f; unsigned int i; } v; v.f = f;
  unsigned int x = v.i;
  return (u16)((x + 0x7fffu + ((x >> 16) & 1u)) >> 16);  // RNE
}

DEV f32x4 mfma16(bf16x8 a, bf16x8 b, f32x4 c) {
  return __builtin_amdgcn_mfma_f32_16x16x32_bf16(a, b, c, 0, 0, 0);
}

DEV void gload_lds16(const void* g, void* s) {
  __builtin_amdgcn_global_load_lds(
      (const __attribute__((address_space(1))) void*)g,
      (__attribute__((address_space(3))) void*)s, 16, 0, 0);
}

DEV float exp2_fast(float x) { float r; asm("v_exp_f32 %0, %1" : "=v"(r) : "v"(x)); return r; }
DEV unsigned cvt_pk_bf16(float lo, float hi) {
  unsigned r;
  asm("v_cvt_pk_bf16_f32 %0, %1, %2" : "=v"(r) : "v"(lo), "v"(hi));
  return r;
}

// ---------------- prep kernels ----------------

__global__ void cast_x_kernel(const float* __restrict__ in, u16* __restrict__ out, int n8) {
  int i = blockIdx.x * blockDim.x + threadIdx.x;
  if (i >= n8) return;
  const float4* p = (const float4*)in + (size_t)i * 2;
  float4 a = p[0], b = p[1];
  short8 o;
  o[0] = (short)f2bf(a.x); o[1] = (short)f2bf(a.y); o[2] = (short)f2bf(a.z); o[3] = (short)f2bf(a.w);
  o[4] = (short)f2bf(b.x); o[5] = (short)f2bf(b.y); o[6] = (short)f2bf(b.z); o[7] = (short)f2bf(b.w);
  *(short8*)(out + (size_t)i * 8) = o;
}

// transpose+cast weights: WT[n][k] = w[k][n], bf16, K-major
__global__ void wt_transpose(const float* __restrict__ wq, const float* __restrict__ wk,
                             const float* __restrict__ wv, const float* __restrict__ wo,
                             u16* __restrict__ wtqkv, u16* __restrict__ wtout) {
  __shared__ float tile[64][65];
  int z = blockIdx.z;
  const float* src = (z == 0) ? wq : (z == 1) ? wk : (z == 2) ? wv : wo;
  int k0 = blockIdx.x * 64, n0 = blockIdx.y * 64;
  int c = threadIdx.x & 63, rq = threadIdx.x >> 6;
#pragma unroll
  for (int p = 0; p < 16; ++p) {
    int r = p * 4 + rq;                       // k-local
    tile[r][c] = src[(size_t)(k0 + r) * 1024 + n0 + c];
  }
  __syncthreads();
  u16* dst = (z < 3) ? (wtqkv + (size_t)z * 1024 * 1024) : wtout;
#pragma unroll
  for (int p = 0; p < 16; ++p) {
    int r = p * 4 + rq;                       // n-local
    dst[(size_t)(n0 + r) * 1024 + k0 + c] = f2bf(tile[c][r]);
  }
}

__global__ void rope_table_kernel(float* __restrict__ cost, float* __restrict__ sint) {
  int i = blockIdx.x * blockDim.x + threadIdx.x;
  if (i >= 1024 * 32) return;
  int pos = i >> 5, d = i & 31;
  float inv = powf(10000.0f, -(float)d / 32.0f);
  float ang = (float)pos * inv;
  cost[i] = cosf(ang);
  sint[i] = sinf(ang);
}

#define QSCALE (0.125f * 1.44269504088896341f)

// ---------------- 256x256 bf16 MFMA GEMM, 8 waves, swizzled LDS, async staging ----
DEV void stage_issue(const u16* __restrict__ gtile, char* dst, int wid, int lane, int s) {
  int tt = wid * 64 + lane;
  int row = s * 64 + (tt >> 3);
  int cs = (((tt & 7) ^ (row & 7)) << 3);       // pre-swizzled source col (elems)
  gload_lds16(gtile + (size_t)row * 1024 + cs, dst + s * 8192 + wid * 1024);
}

__global__ __launch_bounds__(512, 2) void gemm256(const u16* __restrict__ A,
    const u16* __restrict__ Bw, u16* __restrict__ Cout) {
  __shared__ char lds[131072];   // A dbuf 2x32KB | B dbuf 2x32KB
  int mt, nt;
  {
    int orig = blockIdx.x;
    int xcd = orig & 7;
    int f = (xcd < 4 ? xcd * 50 : 200 + (xcd - 4) * 49) + (orig >> 3);
    if (f < 384) { int sr = f / 48, rem = f % 48; nt = rem >> 2; mt = sr * 4 + (rem & 3); }
    else { mt = 32; nt = f - 384; }
  }
  const int t = threadIdx.x;
  const int wid = t >> 6, lane = t & 63;
  const int l4 = lane >> 4, l15 = lane & 15;
  const int wrow = wid >> 2, wcol = wid & 3;    // 2M x 4N waves
  const long rowA0 = (long)mt * 256;
  const long rowB0 = (long)nt * 256;

  f32x4 acc[8][4];
#pragma unroll
  for (int m = 0; m < 8; ++m)
#pragma unroll
    for (int n = 0; n < 4; ++n) { f32x4 z = {0.f,0.f,0.f,0.f}; acc[m][n] = z; }

#pragma unroll
  for (int s = 0; s < 4; ++s) stage_issue(A  + rowA0 * 1024, lds,         wid, lane, s);
#pragma unroll
  for (int s = 0; s < 4; ++s) stage_issue(Bw + rowB0 * 1024, lds + 65536, wid, lane, s);
  asm volatile("s_waitcnt vmcnt(0)" ::: "memory");
  __syncthreads();

  int cur = 0;
  for (int kt = 0; kt < 16; ++kt) {
    const char* Al = lds + cur * 32768;
    const char* Bl = lds + 65536 + cur * 32768;
    char* An = lds + (cur ^ 1) * 32768;
    char* Bn = lds + 65536 + (cur ^ 1) * 32768;
    const u16* gA = A  + rowA0 * 1024 + (kt + 1) * 64;
    const u16* gB = Bw + rowB0 * 1024 + (kt + 1) * 64;
    const bool pf = kt < 15;

#pragma unroll
    for (int kk = 0; kk < 2; ++kk) {
      bf16x8 bfr[4];
#pragma unroll
      for (int n = 0; n < 4; ++n) {
        int r = wcol * 64 + n * 16 + l15;
        bfr[n] = *(const bf16x8*)(Bl + r * 128 + ((kk * 64 + l4 * 16) ^ ((r & 7) << 4)));
      }
#pragma unroll
      for (int mh = 0; mh < 2; ++mh) {
        if (pf) {
          if (kk == 0 && mh == 0) { stage_issue(gA, An, wid, lane, 0); stage_issue(gA, An, wid, lane, 1); }
          if (kk == 0 && mh == 1) { stage_issue(gA, An, wid, lane, 2); stage_issue(gA, An, wid, lane, 3); }
          if (kk == 1 && mh == 0) { stage_issue(gB, Bn, wid, lane, 0); stage_issue(gB, Bn, wid, lane, 1); }
          if (kk == 1 && mh == 1) { stage_issue(gB, Bn, wid, lane, 2); stage_issue(gB, Bn, wid, lane, 3); }
        }
        bf16x8 af[4];
#pragma unroll
        for (int m = 0; m < 4; ++m) {
          int r = wrow * 128 + (mh * 4 + m) * 16 + l15;
          af[m] = *(const bf16x8*)(Al + r * 128 + ((kk * 64 + l4 * 16) ^ ((r & 7) << 4)));
        }
        __builtin_amdgcn_s_setprio(1);
#pragma unroll
        for (int m = 0; m < 4; ++m)
#pragma unroll
          for (int n = 0; n < 4; ++n)
            acc[mh * 4 + m][n] = mfma16(af[m], bfr[n], acc[mh * 4 + m][n]);
        __builtin_amdgcn_s_setprio(0);
      }
    }
    asm volatile("s_waitcnt vmcnt(0)" ::: "memory");
    __syncthreads();
    cur ^= 1;
  }

#pragma unroll
  for (int m = 0; m < 8; ++m)
#pragma unroll
    for (int rg = 0; rg < 4; ++rg) {
      long row = rowA0 + wrow * 128 + m * 16 + l4 * 4 + rg;
      if (row >= MROWS) continue;
#pragma unroll
      for (int n = 0; n < 4; ++n) {
        long col = rowB0 + wcol * 64 + n * 16 + l15;
        Cout[row * 3072 + col] = f2bf(acc[m][n][rg]);
      }
    }
}

// flat f -> (mt, nt): 8-Mtile super-rows (for gemm_out's 65x8 grid)
DEV void map_tiles(int f, int MT, int NT, int& mt, int& nt) {
  int body = (MT & ~7) * NT;
  if (f >= body) { int r = f - body; mt = (MT & ~7) + r / NT; nt = r % NT; }
  else { int sr = f / (8 * NT); int rem = f - sr * 8 * NT; nt = rem >> 3; mt = sr * 8 + (rem & 7); }
}

// ---------------- out-projection GEMM (f32 out + bias), 128^2 m97 structure ----------------
__global__ __launch_bounds__(256) void gemm_out(const u16* __restrict__ A,
    const u16* __restrict__ Bw, float* __restrict__ Cout, const float* __restrict__ bias) {
  __shared__ char smem[32768];
  int mt, nt;
  { int wg = blockIdx.x; int f = (wg & 7) * 65 + (wg >> 3); map_tiles(f, 65, 8, mt, nt); }
  const int t = threadIdx.x;
  const int wid = t >> 6, lane = t & 63;
  const int l4 = lane >> 4, l15 = lane & 15;
  const int wr = wid >> 1, wc = wid & 1;
  const long rowA0 = (long)mt * 128;
  const long rowB0 = (long)nt * 128;

  f32x4 acc[4][4];
#pragma unroll
  for (int m = 0; m < 4; ++m)
#pragma unroll
    for (int n = 0; n < 4; ++n) { f32x4 z = {0.f,0.f,0.f,0.f}; acc[m][n] = z; }

  const int srow = t >> 3;
  const int scol = (t & 7) * 8;

  for (int k0 = 0; k0 < 1024; k0 += 64) {
    __syncthreads();
#pragma unroll
    for (int i = 0; i < 4; ++i) {
      const u16* ga = A  + (rowA0 + i * 32 + srow) * 1024 + k0 + scol;
      gload_lds16(ga, smem + i * 4096 + wid * 1024);
      const u16* gb = Bw + (rowB0 + i * 32 + srow) * 1024 + k0 + scol;
      gload_lds16(gb, smem + 16384 + i * 4096 + wid * 1024);
    }
    __syncthreads();

    bf16x8 af[4][2], bfr[4][2];
#pragma unroll
    for (int m = 0; m < 4; ++m)
#pragma unroll
      for (int kk = 0; kk < 2; ++kk)
        af[m][kk] = *(const bf16x8*)(smem + (wr * 64 + m * 16 + l15) * 128 + kk * 64 + l4 * 16);
#pragma unroll
    for (int n = 0; n < 4; ++n)
#pragma unroll
      for (int kk = 0; kk < 2; ++kk)
        bfr[n][kk] = *(const bf16x8*)(smem + 16384 + (wc * 64 + n * 16 + l15) * 128 + kk * 64 + l4 * 16);

#pragma unroll
    for (int m = 0; m < 4; ++m)
#pragma unroll
      for (int n = 0; n < 4; ++n)
#pragma unroll
        for (int kk = 0; kk < 2; ++kk)
          acc[m][n] = mfma16(af[m][kk], bfr[n][kk], acc[m][n]);
  }

#pragma unroll
  for (int m = 0; m < 4; ++m)
#pragma unroll
    for (int rg = 0; rg < 4; ++rg) {
      long row = rowA0 + wr * 64 + m * 16 + l4 * 4 + rg;
      if (row >= MROWS) continue;
#pragma unroll
      for (int n = 0; n < 4; ++n) {
        long col = rowB0 + wc * 64 + n * 16 + l15;
        Cout[row * 1024 + col] = acc[m][n][rg] + bias[col];
      }
    }
}

// ---------------- RoPE + scale + head-split for Q,K ----------------
__global__ void rope_qk(const u16* __restrict__ cq, const float* __restrict__ qb,
                        const float* __restrict__ cost, const float* __restrict__ sint,
                        u16* __restrict__ Qh, u16* __restrict__ Kh) {
  int idx = blockIdx.x * 256 + threadIdx.x;   // (b*1025+n)*16 + h
  if (idx >= MROWS * NHEAD) return;
  int h = idx & 15, row = idx >> 4;
  int b = row / SEQ, n = row - b * SEQ;
  const u16* src = cq + (size_t)row * 3072 + h * 64;
  size_t dq = ((size_t)(b * 16 + h) * SEQ   + n) * 64;
  size_t dk = ((size_t)(b * 16 + h) * KROWS + n) * 64;
  bool dorope = (n > 0);
  const float* ct = cost + (size_t)(n - 1) * 32;
  const float* st = sint + (size_t)(n - 1) * 32;
#pragma unroll
  for (int i = 0; i < 4; ++i) {
    short8 qlo = *(const short8*)(src + i * 8);
    short8 qhi = *(const short8*)(src + 32 + i * 8);
    short8 klo = *(const short8*)(src + 1024 + i * 8);
    short8 khi = *(const short8*)(src + 1024 + 32 + i * 8);
    short8 oqlo, oqhi, oklo, okhi;
#pragma unroll
    for (int j = 0; j < 8; ++j) {
      int d = i * 8 + j;
      float q1 = bf2f((u16)qlo[j]) + qb[h * 64 + d];
      float q2 = bf2f((u16)qhi[j]) + qb[h * 64 + 32 + d];
      float k1 = bf2f((u16)klo[j]);
      float k2 = bf2f((u16)khi[j]);
      float c = dorope ? ct[d] : 1.0f;
      float s = dorope ? st[d] : 0.0f;
      oqlo[j] = (short)f2bf((q1 * c - q2 * s) * QSCALE);
      oqhi[j] = (short)f2bf((q1 * s + q2 * c) * QSCALE);
      oklo[j] = (short)f2bf(k1 * c - k2 * s);
      okhi[j] = (short)f2bf(k1 * s + k2 * c);
    }
    *(short8*)(Qh + dq + i * 8)      = oqlo;
    *(short8*)(Qh + dq + 32 + i * 8) = oqhi;
    *(short8*)(Kh + dk + i * 8)      = oklo;
    *(short8*)(Kh + dk + 32 + i * 8) = okhi;
  }
}

// ---------------- V: bias + per-head transpose to VT[bh][d][VPAD] ----------------
__global__ void v_transpose(const u16* __restrict__ cq, const float* __restrict__ vb,
                            u16* __restrict__ VTh) {
  __shared__ float tile[64][65];
  int bh = blockIdx.y, b = bh >> 4, h = bh & 15;
  int n0 = blockIdx.x * 64;
  int c = threadIdx.x & 63, rq = threadIdx.x >> 6;
#pragma unroll
  for (int p = 0; p < 16; ++p) {
    int r = p * 4 + rq;
    int n = n0 + r;
    float v = 0.f;
    if (n < SEQ) v = bf2f(cq[(size_t)(b * SEQ + n) * 3072 + 2048 + h * 64 + c]) + vb[h * 64 + c];
    tile[r][c] = v;
  }
  __syncthreads();
#pragma unroll
  for (int p = 0; p < 16; ++p) {
    int d = p * 4 + rq;
    VTh[((size_t)bh * 64 + d) * VPAD + n0 + c] = f2bf(tile[c][d]);
  }
}

// ---------------- flash attention: K/V LDS triple-buffered, counted vmcnt + lgkmcnt ----------------
DEV void stage_rows(const u16* __restrict__ g, size_t strideElems, char* lbase,
                    int wid, int lane) {
#pragma unroll
  for (int s = 0; s < 2; ++s) {
    int off = s * 4096 + wid * 1024 + lane * 16;
    int r = off >> 7, cs = (off >> 4) & 7;
    const u16* src = g + (size_t)r * strideElems + ((cs ^ (r & 7)) << 3);
    gload_lds16(src, lbase + s * 4096 + wid * 1024);
  }
}

__global__ __launch_bounds__(256, 3) void attn128(const u16* __restrict__ Qh,
    const u16* __restrict__ Kh, const u16* __restrict__ VTh,
    u16* __restrict__ xattn) {
  __shared__ char lds[49152];  // K tbuf 3x8KB | V tbuf 3x8KB
  const int wg = blockIdx.x;
  const int x = (wg & 7) * 144 + (wg >> 3);
  const int qt = x % 9, bh = x / 9;
  const int b = bh >> 4, h = bh & 15;
  const int t = threadIdx.x, w = t >> 6, lane = t & 63;
  const int l4 = lane >> 4, l15 = lane & 15;
  const u16* Qb = Qh + (size_t)bh * (SEQ * 64);
  const u16* Kb = Kh + (size_t)bh * (KROWS * 64);
  const u16* Vb = VTh + (size_t)bh * (64 * VPAD);
  const int q0 = qt * 128 + w * 32;
  const int srcb = l15 + ((l4 & 1) << 5);
  const bool hi4 = (l4 >> 1) != 0;

  bf16x8 aq[2][2];
#pragma unroll
  for (int m = 0; m < 2; ++m) {
    int qr = q0 + m * 16 + l15; if (qr > SEQ - 1) qr = SEQ - 1;
    aq[m][0] = *(const bf16x8*)(Qb + (size_t)qr * 64 + l4 * 8);
    aq[m][1] = *(const bf16x8*)(Qb + (size_t)qr * 64 + 32 + l4 * 8);
  }
  bf16x8 ones;
  { union { unsigned u[4]; bf16x8 v; } ou;
    ou.u[0] = ou.u[1] = ou.u[2] = ou.u[3] = 0x3F803F80u; ones = ou.v; }

  f32x4 o[2][4], osum[2];
  float mrow[2];
#pragma unroll
  for (int m = 0; m < 2; ++m) {
#pragma unroll
    for (int n = 0; n < 4; ++n) { f32x4 z = {0.f,0.f,0.f,0.f}; o[m][n] = z; }
    f32x4 z = {0.f,0.f,0.f,0.f}; osum[m] = z;
    mrow[m] = -1e30f;
  }

  // prologue: stage tile 0, PIN ISSUE ORDER, stage tile 1; drain tile 0 only.
  stage_rows(Kb,                   64,   lds,                w, lane);
  stage_rows(Vb,                   VPAD, lds + 24576,        w, lane);
  __builtin_amdgcn_sched_barrier(0);   // tile0's 4 loads must be issued before tile1's
  stage_rows(Kb + (size_t)64 * 64, 64,   lds + 8192,         w, lane);
  stage_rows(Vb + 64,              VPAD, lds + 24576 + 8192, w, lane);
  asm volatile("s_waitcnt vmcnt(4) lgkmcnt(0)\n\ts_barrier" ::: "memory");

  int cur = 0;
  for (int kt = 0; kt < 17; ++kt) {
    const int kb = kt * 64;
    // stage tile kt+2 into buffer (cur+2)%3 (2 ahead); its 4 loads are the newest
    if (kt < 15) {
      int nb = cur + 2; if (nb >= 3) nb -= 3;
      stage_rows(Kb + (size_t)(kb + 128) * 64, 64,   lds + nb * 8192,         w, lane);
      stage_rows(Vb + (kb + 128),              VPAD, lds + 24576 + nb * 8192, w, lane);
    }
    const char* Kl = lds + cur * 8192;
    const char* Vl = lds + 24576 + cur * 8192;

    f32x4 s[2][4];
#pragma unroll
    for (int tt = 0; tt < 4; ++tt) {
      const int kr = tt * 16 + l15;
      const char* kp = Kl + kr * 128;
      bf16x8 bk0 = *(const bf16x8*)(kp + ((l4       ^ (kr & 7)) << 4));
      bf16x8 bk1 = *(const bf16x8*)(kp + (((4 + l4) ^ (kr & 7)) << 4));
#pragma unroll
      for (int m = 0; m < 2; ++m) {
        f32x4 z = {0.f,0.f,0.f,0.f};
        z = mfma16(bk0, aq[m][0], z);
        z = mfma16(bk1, aq[m][1], z);
        s[m][tt] = z;
      }
    }

    if (kt == 16) {   // only key 1024 valid in last tile
#pragma unroll
      for (int m = 0; m < 2; ++m) {
        s[m][0][0] = (l4 == 0) ? s[m][0][0] : -1e30f;
        s[m][0][1] = -1e30f; s[m][0][2] = -1e30f; s[m][0][3] = -1e30f;
#pragma unroll
        for (int tt = 1; tt < 4; ++tt) {
          s[m][tt][0] = -1e30f; s[m][tt][1] = -1e30f; s[m][tt][2] = -1e30f; s[m][tt][3] = -1e30f;
        }
      }
    }

    float tmax[2];
#pragma unroll
    for (int m = 0; m < 2; ++m) {
      float a0 = fmaxf(fmaxf(s[m][0][0], s[m][0][1]), fmaxf(s[m][0][2], s[m][0][3]));
      float a1 = fmaxf(fmaxf(s[m][1][0], s[m][1][1]), fmaxf(s[m][1][2], s[m][1][3]));
      float a2 = fmaxf(fmaxf(s[m][2][0], s[m][2][1]), fmaxf(s[m][2][2], s[m][2][3]));
      float a3 = fmaxf(fmaxf(s[m][3][0], s[m][3][1]), fmaxf(s[m][3][2], s[m][3][3]));
      float tm = fmaxf(fmaxf(a0, a1), fmaxf(a2, a3));
      tm = fmaxf(tm, __shfl_xor(tm, 16));
      tm = fmaxf(tm, __shfl_xor(tm, 32));
      tmax[m] = tm;
    }

    int needR = (tmax[0] > mrow[0] + 8.0f) || (tmax[1] > mrow[1] + 8.0f);
    if (__any(needR)) {
#pragma unroll
      for (int m = 0; m < 2; ++m) {
        float mnew = fmaxf(mrow[m], tmax[m]);
        float alpha = exp2_fast(mrow[m] - mnew);
        mrow[m] = mnew;
        float al[4];
#pragma unroll
        for (int rg = 0; rg < 4; ++rg) al[rg] = __shfl(alpha, l4 * 4 + rg);
#pragma unroll
        for (int n = 0; n < 4; ++n)
#pragma unroll
          for (int rg = 0; rg < 4; ++rg) o[m][n][rg] *= al[rg];
#pragma unroll
        for (int rg = 0; rg < 4; ++rg) osum[m][rg] *= al[rg];
      }
    }

    unsigned pk[2][4][2];
#pragma unroll
    for (int m = 0; m < 2; ++m)
#pragma unroll
      for (int tt = 0; tt < 4; ++tt) {
        float p0 = exp2_fast(s[m][tt][0] - mrow[m]);
        float p1 = exp2_fast(s[m][tt][1] - mrow[m]);
        float p2 = exp2_fast(s[m][tt][2] - mrow[m]);
        float p3 = exp2_fast(s[m][tt][3] - mrow[m]);
        pk[m][tt][0] = cvt_pk_bf16(p0, p1);
        pk[m][tt][1] = cvt_pk_bf16(p2, p3);
      }

#pragma unroll
    for (int kk = 0; kk < 2; ++kk) {
      bf16x8 pa[2];
#pragma unroll
      for (int m = 0; m < 2; ++m) {
        union { unsigned u[4]; bf16x8 v; } pu;
#pragma unroll
        for (int bb = 0; bb < 2; ++bb)
#pragma unroll
          for (int pr = 0; pr < 2; ++pr) {
            unsigned t0 = (unsigned)__shfl((int)pk[m][2 * kk][pr],     srcb + bb * 16);
            unsigned t1 = (unsigned)__shfl((int)pk[m][2 * kk + 1][pr], srcb + bb * 16);
            pu.u[bb * 2 + pr] = hi4 ? t1 : t0;
          }
        pa[m] = pu.v;
      }
#pragma unroll
      for (int n = 0; n < 4; ++n) {
        const int vr = n * 16 + l15;
        bf16x8 bv = *(const bf16x8*)(Vl + vr * 128 + (((kk * 4 + l4) ^ (vr & 7)) << 4));
#pragma unroll
        for (int m = 0; m < 2; ++m)
          o[m][n] = mfma16(pa[m], bv, o[m][n]);
      }
#pragma unroll
      for (int m = 0; m < 2; ++m)
        osum[m] = mfma16(pa[m], ones, osum[m]);
    }

    // counted drain: oldest 4 outstanding = tile kt+1's loads; tile kt+2's stay in flight.
    // lgkmcnt(0) drains this wave's LDS reads before the barrier (prevents the
    // next iteration's DMA from overwriting a buffer with reads still queued).
    if (kt < 15) {
      asm volatile("s_waitcnt vmcnt(4) lgkmcnt(0)\n\ts_barrier" ::: "memory");
    } else if (kt == 15) {
      asm volatile("s_waitcnt vmcnt(0) lgkmcnt(0)\n\ts_barrier" ::: "memory");
    }
    if (++cur == 3) cur = 0;
  }

#pragma unroll
  for (int m = 0; m < 2; ++m)
#pragma unroll
    for (int n = 0; n < 4; ++n)
#pragma unroll
      for (int rg = 0; rg < 4; ++rg) {
        int qrow = q0 + m * 16 + l4 * 4 + rg;
        if (qrow < SEQ)
          xattn[(size_t)(b * SEQ + qrow) * 1024 + h * 64 + n * 16 + l15] =
              f2bf(o[m][n][rg] / osum[m][rg]);
      }
}

// ---------------- launch ----------------

extern "C" void kernel_launch(void* const* d_in, const int* in_sizes, int n_in,
                              void* d_out, int out_size, void* d_ws, size_t ws_size,
                              hipStream_t stream) {
  const float* x      = (const float*)d_in[0];
  const float* wq     = (const float*)d_in[1];
  const float* wk     = (const float*)d_in[2];
  const float* wv     = (const float*)d_in[3];
  const float* q_bias = (const float*)d_in[4];
  const float* v_bias = (const float*)d_in[5];
  const float* w_out  = (const float*)d_in[6];
  const float* b_out  = (const float*)d_in[7];

  char* ws = (char*)d_ws;
  size_t off = 0;
  auto alc = [&](size_t bytes) { size_t r = off; off += (bytes + 255) & ~(size_t)255; return r; };

  u16*  x_bf  = (u16*)(ws + alc((size_t)MROWS * 1024 * 2));
  u16*  wtqkv = (u16*)(ws + alc((size_t)3072 * 1024 * 2));
  u16*  wtout = (u16*)(ws + alc((size_t)1024 * 1024 * 2));
  u16*  xattn = (u16*)(ws + alc((size_t)MROWS * 1024 * 2));
  u16*  cqkv  = (u16*)(ws + alc((size_t)8448 * 3072 * 2));   // padded to 33*256 rows
  u16*  Qhp   = (u16*)(ws + alc((size_t)128 * SEQ * 64 * 2));
  u16*  Khp   = (u16*)(ws + alc((size_t)128 * KROWS * 64 * 2));
  u16*  VThp  = (u16*)(ws + alc((size_t)128 * 64 * VPAD * 2));
  float* cost = (float*)(ws + alc((size_t)1024 * 32 * 4));
  float* sint = (float*)(ws + alc((size_t)1024 * 32 * 4));
  (void)ws_size; (void)in_sizes; (void)n_in; (void)out_size;

  // 1. cast x to bf16
  cast_x_kernel<<<4100, 256, 0, stream>>>(x, x_bf, MROWS * 1024 / 8);
  // 2. weights -> K-major bf16
  wt_transpose<<<dim3(16, 16, 4), 256, 0, stream>>>(wq, wk, wv, w_out, wtqkv, wtout);
  // 3. rope tables
  rope_table_kernel<<<128, 256, 0, stream>>>(cost, sint);
  // 4. fused QKV projection: 256^2 tiles, 33x12 = 396 blocks
  gemm256<<<dim3(396), 512, 0, stream>>>(x_bf, wtqkv, cqkv);
  // 5. rope + scale(+log2e) + head split for Q,K
  rope_qk<<<513, 256, 0, stream>>>(cqkv, q_bias, cost, sint, Qhp, Khp);
  // 6. V bias + per-head transpose (zero-padded keys)
  v_transpose<<<dim3(18, 128), 256, 0, stream>>>(cqkv, v_bias, VThp);
  // 7. flash attention (XCD-swizzled 1D grid: 9 q-tiles x 128 bh; triple-buffered)
  attn128<<<dim3(1152), 256, 0, stream>>>(Qhp, Khp, VThp, xattn);
  // 8. output projection + bias -> d_out (fp32)
  gemm_out<<<dim3(520), 256, 0, stream>>>(xattn, wtout, (float*)d_out, b_out);
}

// Round 13
// 249.083 us; speedup vs baseline: 1.0485x; 1.0485x over previous
//
#include <hip/hip_runtime.h>

typedef unsigned short u16;
typedef __attribute__((ext_vector_type(8))) short  short8;
typedef __attribute__((ext_vector_type(8))) __bf16 bf16x8;
typedef __attribute__((ext_vector_type(4))) float  f32x4;

#define DEV __device__ __forceinline__

// B=8, N=1025, D=1024, H=16, Dh=64
#define BATCH 8
#define SEQ   1025
#define DMODEL 1024
#define NHEAD 16
#define DH    64
#define MROWS (BATCH*SEQ)      // 8200
#define VPAD  1152             // key padding for VT
#define KROWS 1088             // padded K row stride (17*64)

DEV float bf2f(u16 u) { union { unsigned int i; float f; } v; v.i = ((unsigned int)u) << 16; return v.f; }
DEV u16 f2bf(float f) {
  union { float f; unsigned int i; } v; v.f = f;
  unsigned int x = v.i;
  return (u16)((x + 0x7fffu + ((x >> 16) & 1u)) >> 16);  // RNE
}

DEV f32x4 mfma16(bf16x8 a, bf16x8 b, f32x4 c) {
  return __builtin_amdgcn_mfma_f32_16x16x32_bf16(a, b, c, 0, 0, 0);
}

DEV void gload_lds16(const void* g, void* s) {
  __builtin_amdgcn_global_load_lds(
      (const __attribute__((address_space(1))) void*)g,
      (__attribute__((address_space(3))) void*)s, 16, 0, 0);
}

DEV float exp2_fast(float x) { float r; asm("v_exp_f32 %0, %1" : "=v"(r) : "v"(x)); return r; }
DEV unsigned cvt_pk_bf16(float lo, float hi) {
  unsigned r;
  asm("v_cvt_pk_bf16_f32 %0, %1, %2" : "=v"(r) : "v"(lo), "v"(hi));
  return r;
}

#define QSCALE (0.125f * 1.44269504088896341f)

// ---------------- merged prep: cast_x | weight transpose | rope tables ----------------
// blocks [0,4100): cast x; [4100,5124): wt transpose; [5124,5252): rope tables
__global__ void prep_kernel(const float* __restrict__ x,
                            const float* __restrict__ wq, const float* __restrict__ wk,
                            const float* __restrict__ wv, const float* __restrict__ wo,
                            u16* __restrict__ x_bf, u16* __restrict__ wtqkv,
                            u16* __restrict__ wtout,
                            float* __restrict__ cost, float* __restrict__ sint) {
  __shared__ float tile[64][65];
  const int blk = blockIdx.x, tid = threadIdx.x;
  if (blk < 4100) {
    // cast x -> bf16, 8 elems/thread
    int i = blk * 256 + tid;
    if (i >= MROWS * 1024 / 8) return;
    const float4* p = (const float4*)x + (size_t)i * 2;
    float4 a = p[0], b = p[1];
    short8 o;
    o[0] = (short)f2bf(a.x); o[1] = (short)f2bf(a.y); o[2] = (short)f2bf(a.z); o[3] = (short)f2bf(a.w);
    o[4] = (short)f2bf(b.x); o[5] = (short)f2bf(b.y); o[6] = (short)f2bf(b.z); o[7] = (short)f2bf(b.w);
    *(short8*)(x_bf + (size_t)i * 8) = o;
  } else if (blk < 5124) {
    // weight transpose+cast: WT[n][k] = w[k][n]
    int wg = blk - 4100;
    int z = wg >> 8, rem = wg & 255;
    int kx = rem & 15, ny = rem >> 4;
    const float* src = (z == 0) ? wq : (z == 1) ? wk : (z == 2) ? wv : wo;
    int k0 = kx * 64, n0 = ny * 64;
    int c = tid & 63, rq = tid >> 6;
#pragma unroll
    for (int p = 0; p < 16; ++p) {
      int r = p * 4 + rq;
      tile[r][c] = src[(size_t)(k0 + r) * 1024 + n0 + c];
    }
    __syncthreads();
    u16* dst = (z < 3) ? (wtqkv + (size_t)z * 1024 * 1024) : wtout;
#pragma unroll
    for (int p = 0; p < 16; ++p) {
      int r = p * 4 + rq;
      dst[(size_t)(n0 + r) * 1024 + k0 + c] = f2bf(tile[c][r]);
    }
  } else {
    // rope tables
    int i = (blk - 5124) * 256 + tid;
    if (i >= 1024 * 32) return;
    int pos = i >> 5, d = i & 31;
    float inv = powf(10000.0f, -(float)d / 32.0f);
    float ang = (float)pos * inv;
    cost[i] = cosf(ang);
    sint[i] = sinf(ang);
  }
}

// ---------------- 256x256 bf16 MFMA GEMM, 8 waves, swizzled LDS, async staging ----
DEV void stage_issue(const u16* __restrict__ gtile, char* dst, int wid, int lane, int s) {
  int tt = wid * 64 + lane;
  int row = s * 64 + (tt >> 3);
  int cs = (((tt & 7) ^ (row & 7)) << 3);       // pre-swizzled source col (elems)
  gload_lds16(gtile + (size_t)row * 1024 + cs, dst + s * 8192 + wid * 1024);
}

__global__ __launch_bounds__(512, 2) void gemm256(const u16* __restrict__ A,
    const u16* __restrict__ Bw, u16* __restrict__ Cout) {
  __shared__ char lds[131072];   // A dbuf 2x32KB | B dbuf 2x32KB
  int mt, nt;
  {
    int orig = blockIdx.x;
    int xcd = orig & 7;
    int f = (xcd < 4 ? xcd * 50 : 200 + (xcd - 4) * 49) + (orig >> 3);
    if (f < 384) { int sr = f / 48, rem = f % 48; nt = rem >> 2; mt = sr * 4 + (rem & 3); }
    else { mt = 32; nt = f - 384; }
  }
  const int t = threadIdx.x;
  const int wid = t >> 6, lane = t & 63;
  const int l4 = lane >> 4, l15 = lane & 15;
  const int wrow = wid >> 2, wcol = wid & 3;    // 2M x 4N waves
  const long rowA0 = (long)mt * 256;
  const long rowB0 = (long)nt * 256;

  f32x4 acc[8][4];
#pragma unroll
  for (int m = 0; m < 8; ++m)
#pragma unroll
    for (int n = 0; n < 4; ++n) { f32x4 z = {0.f,0.f,0.f,0.f}; acc[m][n] = z; }

#pragma unroll
  for (int s = 0; s < 4; ++s) stage_issue(A  + rowA0 * 1024, lds,         wid, lane, s);
#pragma unroll
  for (int s = 0; s < 4; ++s) stage_issue(Bw + rowB0 * 1024, lds + 65536, wid, lane, s);
  asm volatile("s_waitcnt vmcnt(0)" ::: "memory");
  __syncthreads();

  int cur = 0;
  for (int kt = 0; kt < 16; ++kt) {
    const char* Al = lds + cur * 32768;
    const char* Bl = lds + 65536 + cur * 32768;
    char* An = lds + (cur ^ 1) * 32768;
    char* Bn = lds + 65536 + (cur ^ 1) * 32768;
    const u16* gA = A  + rowA0 * 1024 + (kt + 1) * 64;
    const u16* gB = Bw + rowB0 * 1024 + (kt + 1) * 64;
    const bool pf = kt < 15;

#pragma unroll
    for (int kk = 0; kk < 2; ++kk) {
      bf16x8 bfr[4];
#pragma unroll
      for (int n = 0; n < 4; ++n) {
        int r = wcol * 64 + n * 16 + l15;
        bfr[n] = *(const bf16x8*)(Bl + r * 128 + ((kk * 64 + l4 * 16) ^ ((r & 7) << 4)));
      }
#pragma unroll
      for (int mh = 0; mh < 2; ++mh) {
        if (pf) {
          if (kk == 0 && mh == 0) { stage_issue(gA, An, wid, lane, 0); stage_issue(gA, An, wid, lane, 1); }
          if (kk == 0 && mh == 1) { stage_issue(gA, An, wid, lane, 2); stage_issue(gA, An, wid, lane, 3); }
          if (kk == 1 && mh == 0) { stage_issue(gB, Bn, wid, lane, 0); stage_issue(gB, Bn, wid, lane, 1); }
          if (kk == 1 && mh == 1) { stage_issue(gB, Bn, wid, lane, 2); stage_issue(gB, Bn, wid, lane, 3); }
        }
        bf16x8 af[4];
#pragma unroll
        for (int m = 0; m < 4; ++m) {
          int r = wrow * 128 + (mh * 4 + m) * 16 + l15;
          af[m] = *(const bf16x8*)(Al + r * 128 + ((kk * 64 + l4 * 16) ^ ((r & 7) << 4)));
        }
        __builtin_amdgcn_s_setprio(1);
#pragma unroll
        for (int m = 0; m < 4; ++m)
#pragma unroll
          for (int n = 0; n < 4; ++n)
            acc[mh * 4 + m][n] = mfma16(af[m], bfr[n], acc[mh * 4 + m][n]);
        __builtin_amdgcn_s_setprio(0);
      }
    }
    asm volatile("s_waitcnt vmcnt(0)" ::: "memory");
    __syncthreads();
    cur ^= 1;
  }

#pragma unroll
  for (int m = 0; m < 8; ++m)
#pragma unroll
    for (int rg = 0; rg < 4; ++rg) {
      long row = rowA0 + wrow * 128 + m * 16 + l4 * 4 + rg;
      if (row >= MROWS) continue;
#pragma unroll
      for (int n = 0; n < 4; ++n) {
        long col = rowB0 + wcol * 64 + n * 16 + l15;
        Cout[row * 3072 + col] = f2bf(acc[m][n][rg]);
      }
    }
}

// flat f -> (mt, nt): 8-Mtile super-rows (for gemm_out's 65x8 grid)
DEV void map_tiles(int f, int MT, int NT, int& mt, int& nt) {
  int body = (MT & ~7) * NT;
  if (f >= body) { int r = f - body; mt = (MT & ~7) + r / NT; nt = r % NT; }
  else { int sr = f / (8 * NT); int rem = f - sr * 8 * NT; nt = rem >> 3; mt = sr * 8 + (rem & 7); }
}

// ---------------- out-projection GEMM (f32 out + bias), 128^2 m97 structure ----------------
__global__ __launch_bounds__(256) void gemm_out(const u16* __restrict__ A,
    const u16* __restrict__ Bw, float* __restrict__ Cout, const float* __restrict__ bias) {
  __shared__ char smem[32768];
  int mt, nt;
  { int wg = blockIdx.x; int f = (wg & 7) * 65 + (wg >> 3); map_tiles(f, 65, 8, mt, nt); }
  const int t = threadIdx.x;
  const int wid = t >> 6, lane = t & 63;
  const int l4 = lane >> 4, l15 = lane & 15;
  const int wr = wid >> 1, wc = wid & 1;
  const long rowA0 = (long)mt * 128;
  const long rowB0 = (long)nt * 128;

  f32x4 acc[4][4];
#pragma unroll
  for (int m = 0; m < 4; ++m)
#pragma unroll
    for (int n = 0; n < 4; ++n) { f32x4 z = {0.f,0.f,0.f,0.f}; acc[m][n] = z; }

  const int srow = t >> 3;
  const int scol = (t & 7) * 8;

  for (int k0 = 0; k0 < 1024; k0 += 64) {
    __syncthreads();
#pragma unroll
    for (int i = 0; i < 4; ++i) {
      const u16* ga = A  + (rowA0 + i * 32 + srow) * 1024 + k0 + scol;
      gload_lds16(ga, smem + i * 4096 + wid * 1024);
      const u16* gb = Bw + (rowB0 + i * 32 + srow) * 1024 + k0 + scol;
      gload_lds16(gb, smem + 16384 + i * 4096 + wid * 1024);
    }
    __syncthreads();

    bf16x8 af[4][2], bfr[4][2];
#pragma unroll
    for (int m = 0; m < 4; ++m)
#pragma unroll
      for (int kk = 0; kk < 2; ++kk)
        af[m][kk] = *(const bf16x8*)(smem + (wr * 64 + m * 16 + l15) * 128 + kk * 64 + l4 * 16);
#pragma unroll
    for (int n = 0; n < 4; ++n)
#pragma unroll
      for (int kk = 0; kk < 2; ++kk)
        bfr[n][kk] = *(const bf16x8*)(smem + 16384 + (wc * 64 + n * 16 + l15) * 128 + kk * 64 + l4 * 16);

#pragma unroll
    for (int m = 0; m < 4; ++m)
#pragma unroll
      for (int n = 0; n < 4; ++n)
#pragma unroll
        for (int kk = 0; kk < 2; ++kk)
          acc[m][n] = mfma16(af[m][kk], bfr[n][kk], acc[m][n]);
  }

#pragma unroll
  for (int m = 0; m < 4; ++m)
#pragma unroll
    for (int rg = 0; rg < 4; ++rg) {
      long row = rowA0 + wr * 64 + m * 16 + l4 * 4 + rg;
      if (row >= MROWS) continue;
#pragma unroll
      for (int n = 0; n < 4; ++n) {
        long col = rowB0 + wc * 64 + n * 16 + l15;
        Cout[row * 1024 + col] = acc[m][n][rg] + bias[col];
      }
    }
}

// ---------------- merged post-QKV: rope+head-split (Q,K) | V bias+transpose ----------------
// blocks [0,513): rope_qk; [513, 513+2304): v_transpose (bh = wg/18, n-tile = wg%18)
__global__ void postqkv_kernel(const u16* __restrict__ cq, const float* __restrict__ qb,
                               const float* __restrict__ vb,
                               const float* __restrict__ cost, const float* __restrict__ sint,
                               u16* __restrict__ Qh, u16* __restrict__ Kh,
                               u16* __restrict__ VTh) {
  __shared__ float tile[64][65];
  const int blk = blockIdx.x, tid = threadIdx.x;
  if (blk < 513) {
    int idx = blk * 256 + tid;   // (b*1025+n)*16 + h
    if (idx >= MROWS * NHEAD) return;
    int h = idx & 15, row = idx >> 4;
    int b = row / SEQ, n = row - b * SEQ;
    const u16* src = cq + (size_t)row * 3072 + h * 64;
    size_t dq = ((size_t)(b * 16 + h) * SEQ   + n) * 64;
    size_t dk = ((size_t)(b * 16 + h) * KROWS + n) * 64;
    bool dorope = (n > 0);
    const float* ct = cost + (size_t)(n - 1) * 32;
    const float* st = sint + (size_t)(n - 1) * 32;
#pragma unroll
    for (int i = 0; i < 4; ++i) {
      short8 qlo = *(const short8*)(src + i * 8);
      short8 qhi = *(const short8*)(src + 32 + i * 8);
      short8 klo = *(const short8*)(src + 1024 + i * 8);
      short8 khi = *(const short8*)(src + 1024 + 32 + i * 8);
      short8 oqlo, oqhi, oklo, okhi;
#pragma unroll
      for (int j = 0; j < 8; ++j) {
        int d = i * 8 + j;
        float q1 = bf2f((u16)qlo[j]) + qb[h * 64 + d];
        float q2 = bf2f((u16)qhi[j]) + qb[h * 64 + 32 + d];
        float k1 = bf2f((u16)klo[j]);
        float k2 = bf2f((u16)khi[j]);
        float c = dorope ? ct[d] : 1.0f;
        float s = dorope ? st[d] : 0.0f;
        oqlo[j] = (short)f2bf((q1 * c - q2 * s) * QSCALE);
        oqhi[j] = (short)f2bf((q1 * s + q2 * c) * QSCALE);
        oklo[j] = (short)f2bf(k1 * c - k2 * s);
        okhi[j] = (short)f2bf(k1 * s + k2 * c);
      }
      *(short8*)(Qh + dq + i * 8)      = oqlo;
      *(short8*)(Qh + dq + 32 + i * 8) = oqhi;
      *(short8*)(Kh + dk + i * 8)      = oklo;
      *(short8*)(Kh + dk + 32 + i * 8) = okhi;
    }
  } else {
    int wg = blk - 513;
    int bh = wg / 18, nx = wg - bh * 18;
    int b = bh >> 4, h = bh & 15;
    int n0 = nx * 64;
    int c = tid & 63, rq = tid >> 6;
#pragma unroll
    for (int p = 0; p < 16; ++p) {
      int r = p * 4 + rq;
      int n = n0 + r;
      float v = 0.f;
      if (n < SEQ) v = bf2f(cq[(size_t)(b * SEQ + n) * 3072 + 2048 + h * 64 + c]) + vb[h * 64 + c];
      tile[r][c] = v;
    }
    __syncthreads();
#pragma unroll
    for (int p = 0; p < 16; ++p) {
      int d = p * 4 + rq;
      VTh[((size_t)bh * 64 + d) * VPAD + n0 + c] = f2bf(tile[c][d]);
    }
  }
}

// ---------------- flash attention: round-6 proven structure (dbuf, online max) ----------------
DEV void stage_rows(const u16* __restrict__ g, size_t strideElems, char* lbase,
                    int wid, int lane) {
#pragma unroll
  for (int s = 0; s < 2; ++s) {
    int off = s * 4096 + wid * 1024 + lane * 16;
    int r = off >> 7, cs = (off >> 4) & 7;
    const u16* src = g + (size_t)r * strideElems + ((cs ^ (r & 7)) << 3);
    gload_lds16(src, lbase + s * 4096 + wid * 1024);
  }
}

__global__ __launch_bounds__(256, 4) void attn128(const u16* __restrict__ Qh,
    const u16* __restrict__ Kh, const u16* __restrict__ VTh,
    u16* __restrict__ xattn) {
  __shared__ char lds[32768];  // K dbuf 16K | V dbuf 16K
  const int wg = blockIdx.x;
  const int x = (wg & 7) * 144 + (wg >> 3);
  const int qt = x % 9, bh = x / 9;
  const int b = bh >> 4, h = bh & 15;
  const int t = threadIdx.x, w = t >> 6, lane = t & 63;
  const int l4 = lane >> 4, l15 = lane & 15;
  const u16* Qb = Qh + (size_t)bh * (SEQ * 64);
  const u16* Kb = Kh + (size_t)bh * (KROWS * 64);
  const u16* Vb = VTh + (size_t)bh * (64 * VPAD);
  const int q0 = qt * 128 + w * 32;
  const int srcb = l15 + ((l4 & 1) << 5);
  const bool hi4 = (l4 >> 1) != 0;

  bf16x8 aq[2][2];
#pragma unroll
  for (int m = 0; m < 2; ++m) {
    int qr = q0 + m * 16 + l15; if (qr > SEQ - 1) qr = SEQ - 1;
    aq[m][0] = *(const bf16x8*)(Qb + (size_t)qr * 64 + l4 * 8);
    aq[m][1] = *(const bf16x8*)(Qb + (size_t)qr * 64 + 32 + l4 * 8);
  }
  bf16x8 ones;
  { union { unsigned u[4]; bf16x8 v; } ou;
    ou.u[0] = ou.u[1] = ou.u[2] = ou.u[3] = 0x3F803F80u; ones = ou.v; }

  f32x4 o[2][4], osum[2];
  float mrow[2];
#pragma unroll
  for (int m = 0; m < 2; ++m) {
#pragma unroll
    for (int n = 0; n < 4; ++n) { f32x4 z = {0.f,0.f,0.f,0.f}; o[m][n] = z; }
    f32x4 z = {0.f,0.f,0.f,0.f}; osum[m] = z;
    mrow[m] = -1e30f;
  }

  stage_rows(Kb, 64, lds, w, lane);
  stage_rows(Vb, VPAD, lds + 16384, w, lane);
  asm volatile("s_waitcnt vmcnt(0)" ::: "memory");
  __syncthreads();

  int cur = 0;
  for (int kt = 0; kt < 17; ++kt) {
    const int kb = kt * 64;
    if (kt < 16) {
      stage_rows(Kb + (size_t)(kb + 64) * 64, 64, lds + (cur ^ 1) * 8192, w, lane);
      stage_rows(Vb + (kb + 64), VPAD, lds + 16384 + (cur ^ 1) * 8192, w, lane);
    }
    const char* Kl = lds + cur * 8192;
    const char* Vl = lds + 16384 + cur * 8192;

    f32x4 s[2][4];
#pragma unroll
    for (int tt = 0; tt < 4; ++tt) {
      const int kr = tt * 16 + l15;
      const char* kp = Kl + kr * 128;
      bf16x8 bk0 = *(const bf16x8*)(kp + ((l4       ^ (kr & 7)) << 4));
      bf16x8 bk1 = *(const bf16x8*)(kp + (((4 + l4) ^ (kr & 7)) << 4));
#pragma unroll
      for (int m = 0; m < 2; ++m) {
        f32x4 z = {0.f,0.f,0.f,0.f};
        z = mfma16(bk0, aq[m][0], z);
        z = mfma16(bk1, aq[m][1], z);
        s[m][tt] = z;
      }
    }

    if (kt == 16) {
#pragma unroll
      for (int m = 0; m < 2; ++m) {
        s[m][0][0] = (l4 == 0) ? s[m][0][0] : -1e30f;
        s[m][0][1] = -1e30f; s[m][0][2] = -1e30f; s[m][0][3] = -1e30f;
#pragma unroll
        for (int tt = 1; tt < 4; ++tt) {
          s[m][tt][0] = -1e30f; s[m][tt][1] = -1e30f; s[m][tt][2] = -1e30f; s[m][tt][3] = -1e30f;
        }
      }
    }

    float tmax[2];
#pragma unroll
    for (int m = 0; m < 2; ++m) {
      float a0 = fmaxf(fmaxf(s[m][0][0], s[m][0][1]), fmaxf(s[m][0][2], s[m][0][3]));
      float a1 = fmaxf(fmaxf(s[m][1][0], s[m][1][1]), fmaxf(s[m][1][2], s[m][1][3]));
      float a2 = fmaxf(fmaxf(s[m][2][0], s[m][2][1]), fmaxf(s[m][2][2], s[m][2][3]));
      float a3 = fmaxf(fmaxf(s[m][3][0], s[m][3][1]), fmaxf(s[m][3][2], s[m][3][3]));
      float tm = fmaxf(fmaxf(a0, a1), fmaxf(a2, a3));
      tm = fmaxf(tm, __shfl_xor(tm, 16));
      tm = fmaxf(tm, __shfl_xor(tm, 32));
      tmax[m] = tm;
    }

    int needR = (tmax[0] > mrow[0] + 8.0f) || (tmax[1] > mrow[1] + 8.0f);
    if (__any(needR)) {
#pragma unroll
      for (int m = 0; m < 2; ++m) {
        float mnew = fmaxf(mrow[m], tmax[m]);
        float alpha = exp2_fast(mrow[m] - mnew);
        mrow[m] = mnew;
        float al[4];
#pragma unroll
        for (int rg = 0; rg < 4; ++rg) al[rg] = __shfl(alpha, l4 * 4 + rg);
#pragma unroll
        for (int n = 0; n < 4; ++n)
#pragma unroll
          for (int rg = 0; rg < 4; ++rg) o[m][n][rg] *= al[rg];
#pragma unroll
        for (int rg = 0; rg < 4; ++rg) osum[m][rg] *= al[rg];
      }
    }

    unsigned pk[2][4][2];
#pragma unroll
    for (int m = 0; m < 2; ++m)
#pragma unroll
      for (int tt = 0; tt < 4; ++tt) {
        float p0 = exp2_fast(s[m][tt][0] - mrow[m]);
        float p1 = exp2_fast(s[m][tt][1] - mrow[m]);
        float p2 = exp2_fast(s[m][tt][2] - mrow[m]);
        float p3 = exp2_fast(s[m][tt][3] - mrow[m]);
        pk[m][tt][0] = cvt_pk_bf16(p0, p1);
        pk[m][tt][1] = cvt_pk_bf16(p2, p3);
      }

#pragma unroll
    for (int kk = 0; kk < 2; ++kk) {
      bf16x8 pa[2];
#pragma unroll
      for (int m = 0; m < 2; ++m) {
        union { unsigned u[4]; bf16x8 v; } pu;
#pragma unroll
        for (int bb = 0; bb < 2; ++bb)
#pragma unroll
          for (int pr = 0; pr < 2; ++pr) {
            unsigned t0 = (unsigned)__shfl((int)pk[m][2 * kk][pr],     srcb + bb * 16);
            unsigned t1 = (unsigned)__shfl((int)pk[m][2 * kk + 1][pr], srcb + bb * 16);
            pu.u[bb * 2 + pr] = hi4 ? t1 : t0;
          }
        pa[m] = pu.v;
      }
#pragma unroll
      for (int n = 0; n < 4; ++n) {
        const int vr = n * 16 + l15;
        bf16x8 bv = *(const bf16x8*)(Vl + vr * 128 + (((kk * 4 + l4) ^ (vr & 7)) << 4));
#pragma unroll
        for (int m = 0; m < 2; ++m)
          o[m][n] = mfma16(pa[m], bv, o[m][n]);
      }
#pragma unroll
      for (int m = 0; m < 2; ++m)
        osum[m] = mfma16(pa[m], ones, osum[m]);
    }

    asm volatile("s_waitcnt vmcnt(0)" ::: "memory");
    __syncthreads();
    cur ^= 1;
  }

#pragma unroll
  for (int m = 0; m < 2; ++m)
#pragma unroll
    for (int n = 0; n < 4; ++n)
#pragma unroll
      for (int rg = 0; rg < 4; ++rg) {
        int qrow = q0 + m * 16 + l4 * 4 + rg;
        if (qrow < SEQ)
          xattn[(size_t)(b * SEQ + qrow) * 1024 + h * 64 + n * 16 + l15] =
              f2bf(o[m][n][rg] / osum[m][rg]);
      }
}

// ---------------- launch ----------------

extern "C" void kernel_launch(void* const* d_in, const int* in_sizes, int n_in,
                              void* d_out, int out_size, void* d_ws, size_t ws_size,
                              hipStream_t stream) {
  const float* x      = (const float*)d_in[0];
  const float* wq     = (const float*)d_in[1];
  const float* wk     = (const float*)d_in[2];
  const float* wv     = (const float*)d_in[3];
  const float* q_bias = (const float*)d_in[4];
  const float* v_bias = (const float*)d_in[5];
  const float* w_out  = (const float*)d_in[6];
  const float* b_out  = (const float*)d_in[7];

  char* ws = (char*)d_ws;
  size_t off = 0;
  auto alc = [&](size_t bytes) { size_t r = off; off += (bytes + 255) & ~(size_t)255; return r; };

  u16*  x_bf  = (u16*)(ws + alc((size_t)MROWS * 1024 * 2));
  u16*  wtqkv = (u16*)(ws + alc((size_t)3072 * 1024 * 2));
  u16*  wtout = (u16*)(ws + alc((size_t)1024 * 1024 * 2));
  u16*  xattn = (u16*)(ws + alc((size_t)MROWS * 1024 * 2));
  u16*  cqkv  = (u16*)(ws + alc((size_t)8448 * 3072 * 2));   // padded to 33*256 rows
  u16*  Qhp   = (u16*)(ws + alc((size_t)128 * SEQ * 64 * 2));
  u16*  Khp   = (u16*)(ws + alc((size_t)128 * KROWS * 64 * 2));
  u16*  VThp  = (u16*)(ws + alc((size_t)128 * 64 * VPAD * 2));
  float* cost = (float*)(ws + alc((size_t)1024 * 32 * 4));
  float* sint = (float*)(ws + alc((size_t)1024 * 32 * 4));
  (void)ws_size; (void)in_sizes; (void)n_in; (void)out_size;

  // 1. merged prep: cast x | transpose weights | rope tables
  prep_kernel<<<dim3(5252), 256, 0, stream>>>(x, wq, wk, wv, w_out,
                                              x_bf, wtqkv, wtout, cost, sint);
  // 2. fused QKV projection: 256^2 tiles, 33x12 = 396 blocks
  gemm256<<<dim3(396), 512, 0, stream>>>(x_bf, wtqkv, cqkv);
  // 3. merged post-QKV: rope+head-split (Q,K) | V bias+transpose
  postqkv_kernel<<<dim3(513 + 2304), 256, 0, stream>>>(cqkv, q_bias, v_bias,
                                                       cost, sint, Qhp, Khp, VThp);
  // 4. flash attention (XCD-swizzled 1D grid: 9 q-tiles x 128 bh)
  attn128<<<dim3(1152), 256, 0, stream>>>(Qhp, Khp, VThp, xattn);
  // 5. output projection + bias -> d_out (fp32)
  gemm_out<<<dim3(520), 256, 0, stream>>>(xattn, wtout, (float*)d_out, b_out);
}

// Round 14
// 247.322 us; speedup vs baseline: 1.0559x; 1.0071x over previous
//
#include <hip/hip_runtime.h>

typedef unsigned short u16;
typedef __attribute__((ext_vector_type(8))) short  short8;
typedef __attribute__((ext_vector_type(8))) __bf16 bf16x8;
typedef __attribute__((ext_vector_type(4))) float  f32x4;

#define DEV __device__ __forceinline__

// B=8, N=1025, D=1024, H=16, Dh=64
#define BATCH 8
#define SEQ   1025
#define DMODEL 1024
#define NHEAD 16
#define DH    64
#define MROWS (BATCH*SEQ)      // 8200
#define VPAD  1152             // key padding for VT
#define KROWS 1088             // padded K row stride (17*64)

DEV float bf2f(u16 u) { union { unsigned int i; float f; } v; v.i = ((unsigned int)u) << 16; return v.f; }
DEV u16 f2bf(float f) {
  union { float f; unsigned int i; } v; v.f = f;
  unsigned int x = v.i;
  return (u16)((x + 0x7fffu + ((x >> 16) & 1u)) >> 16);  // RNE
}

DEV f32x4 mfma16(bf16x8 a, bf16x8 b, f32x4 c) {
  return __builtin_amdgcn_mfma_f32_16x16x32_bf16(a, b, c, 0, 0, 0);
}

DEV void gload_lds16(const void* g, void* s) {
  __builtin_amdgcn_global_load_lds(
      (const __attribute__((address_space(1))) void*)g,
      (__attribute__((address_space(3))) void*)s, 16, 0, 0);
}

DEV float exp2_fast(float x) { float r; asm("v_exp_f32 %0, %1" : "=v"(r) : "v"(x)); return r; }
DEV unsigned cvt_pk_bf16(float lo, float hi) {
  unsigned r;
  asm("v_cvt_pk_bf16_f32 %0, %1, %2" : "=v"(r) : "v"(lo), "v"(hi));
  return r;
}

#define QSCALE (0.125f * 1.44269504088896341f)

// ---------------- merged prep: cast_x | weight transpose | rope tables ----------------
__global__ void prep_kernel(const float* __restrict__ x,
                            const float* __restrict__ wq, const float* __restrict__ wk,
                            const float* __restrict__ wv, const float* __restrict__ wo,
                            u16* __restrict__ x_bf, u16* __restrict__ wtqkv,
                            u16* __restrict__ wtout,
                            float* __restrict__ cost, float* __restrict__ sint) {
  __shared__ float tile[64][65];
  const int blk = blockIdx.x, tid = threadIdx.x;
  if (blk < 4100) {
    int i = blk * 256 + tid;
    if (i >= MROWS * 1024 / 8) return;
    const float4* p = (const float4*)x + (size_t)i * 2;
    float4 a = p[0], b = p[1];
    short8 o;
    o[0] = (short)f2bf(a.x); o[1] = (short)f2bf(a.y); o[2] = (short)f2bf(a.z); o[3] = (short)f2bf(a.w);
    o[4] = (short)f2bf(b.x); o[5] = (short)f2bf(b.y); o[6] = (short)f2bf(b.z); o[7] = (short)f2bf(b.w);
    *(short8*)(x_bf + (size_t)i * 8) = o;
  } else if (blk < 5124) {
    int wg = blk - 4100;
    int z = wg >> 8, rem = wg & 255;
    int kx = rem & 15, ny = rem >> 4;
    const float* src = (z == 0) ? wq : (z == 1) ? wk : (z == 2) ? wv : wo;
    int k0 = kx * 64, n0 = ny * 64;
    int c = tid & 63, rq = tid >> 6;
#pragma unroll
    for (int p = 0; p < 16; ++p) {
      int r = p * 4 + rq;
      tile[r][c] = src[(size_t)(k0 + r) * 1024 + n0 + c];
    }
    __syncthreads();
    u16* dst = (z < 3) ? (wtqkv + (size_t)z * 1024 * 1024) : wtout;
#pragma unroll
    for (int p = 0; p < 16; ++p) {
      int r = p * 4 + rq;
      dst[(size_t)(n0 + r) * 1024 + k0 + c] = f2bf(tile[c][r]);
    }
  } else {
    int i = (blk - 5124) * 256 + tid;
    if (i >= 1024 * 32) return;
    int pos = i >> 5, d = i & 31;
    float inv = powf(10000.0f, -(float)d / 32.0f);
    float ang = (float)pos * inv;
    cost[i] = cosf(ang);
    sint[i] = sinf(ang);
  }
}

// ---------------- 256x256 bf16 GEMM, 8-phase schedule (T2+T3+T4+T5) ----------------
// Two 64KB K-tile buffers X(0),Y(1); half-tiles split along K (256 rows x 32 cols,
// 16KB, 2 gload_lds of 8KB). Each phase: fused counted-vmcnt fence + barrier,
// stage 1 half-tile, 8 ds_read_b128, 16 MFMA. Halves staged 4 phases before read.
// Swizzle: LDS byte bits[5:4] ^= row bits[2:1] (2-way conflict = free); inverse
// applied on the pre-swizzled global source (global_load_lds writes linearly).
#define FENCE(N) asm volatile("s_waitcnt vmcnt(" N ") lgkmcnt(0)\n\ts_barrier" ::: "memory")

DEV void stage_half(const u16* __restrict__ gpanel, long row0, int kcol,
                    char* dst, int wid, int lane) {
#pragma unroll
  for (int s = 0; s < 2; ++s) {
    int tt = wid * 64 + lane;
    int row = s * 128 + (tt >> 2), c2 = tt & 3;
    const u16* src = gpanel + (row0 + row) * 1024 + kcol + ((c2 ^ ((row >> 1) & 3)) << 3);
    gload_lds16(src, dst + s * 8192 + wid * 1024);
  }
}

DEV void quad(const char* sm, int buf, int kk, int mh, int wrow, int wcol,
              int l4, int l15, f32x4 (&acc)[8][4]) {
  const char* Ab = sm + buf * 65536 + kk * 16384;
  const char* Bb = sm + buf * 65536 + 32768 + kk * 16384;
  bf16x8 bfr[4];
#pragma unroll
  for (int n = 0; n < 4; ++n) {
    int r = wcol * 64 + n * 16 + l15;
    bfr[n] = *(const bf16x8*)(Bb + r * 64 + ((l4 << 4) ^ (((r >> 1) & 3) << 4)));
  }
  bf16x8 af[4];
#pragma unroll
  for (int m = 0; m < 4; ++m) {
    int r = wrow * 128 + (mh * 4 + m) * 16 + l15;
    af[m] = *(const bf16x8*)(Ab + r * 64 + ((l4 << 4) ^ (((r >> 1) & 3) << 4)));
  }
  __builtin_amdgcn_s_setprio(1);
#pragma unroll
  for (int m = 0; m < 4; ++m)
#pragma unroll
    for (int n = 0; n < 4; ++n)
      acc[mh * 4 + m][n] = mfma16(af[m], bfr[n], acc[mh * 4 + m][n]);
  __builtin_amdgcn_s_setprio(0);
}

__global__ __launch_bounds__(512, 2) void gemm256(const u16* __restrict__ A,
    const u16* __restrict__ Bw, u16* __restrict__ Cout) {
  __shared__ char smem[131072];   // X: A-k0|A-k1|B-k0|B-k1 (16KB each); Y at +65536
  int mt, nt;
  {
    int orig = blockIdx.x;
    int xcd = orig & 7;
    int f = (xcd < 4 ? xcd * 50 : 200 + (xcd - 4) * 49) + (orig >> 3);
    if (f < 384) { int sr = f / 48, rem = f % 48; nt = rem >> 2; mt = sr * 4 + (rem & 3); }
    else { mt = 32; nt = f - 384; }
  }
  const int t = threadIdx.x;
  const int wid = t >> 6, lane = t & 63;
  const int l4 = lane >> 4, l15 = lane & 15;
  const int wrow = wid >> 2, wcol = wid & 3;    // 2M x 4N waves
  const long rowA0 = (long)mt * 256;
  const long rowB0 = (long)nt * 256;

  f32x4 acc[8][4];
#pragma unroll
  for (int m = 0; m < 8; ++m)
#pragma unroll
    for (int n = 0; n < 4; ++n) { f32x4 z = {0.f,0.f,0.f,0.f}; acc[m][n] = z; }

  // prologue: X <- tile 0 (order: A-k0, B-k0, A-k1, B-k1)
  stage_half(A,  rowA0, 0,  smem + 0,     wid, lane);
  stage_half(Bw, rowB0, 0,  smem + 32768, wid, lane);
  stage_half(A,  rowA0, 32, smem + 16384, wid, lane);
  stage_half(Bw, rowB0, 32, smem + 49152, wid, lane);

  // main: iter j covers K-tiles 2j (X) and 2j+1 (Y); stages Y<-2j+1 (ph0-3),
  // X<-2j+2 (ph4-7). Every half staged exactly 4 phases before first read.
  for (int j = 0; j < 7; ++j) {
    const int cY = (2 * j + 1) * 64, cX = (2 * j + 2) * 64;
    FENCE("4"); stage_half(A,  rowA0, cY,      smem + 65536 + 0,     wid, lane); quad(smem, 0, 0, 0, wrow, wcol, l4, l15, acc);
    FENCE("6"); stage_half(Bw, rowB0, cY,      smem + 65536 + 32768, wid, lane); quad(smem, 0, 0, 1, wrow, wcol, l4, l15, acc);
    FENCE("4"); stage_half(A,  rowA0, cY + 32, smem + 65536 + 16384, wid, lane); quad(smem, 0, 1, 0, wrow, wcol, l4, l15, acc);
    FENCE("6"); stage_half(Bw, rowB0, cY + 32, smem + 65536 + 49152, wid, lane); quad(smem, 0, 1, 1, wrow, wcol, l4, l15, acc);
    FENCE("4"); stage_half(A,  rowA0, cX,      smem + 0,     wid, lane); quad(smem, 1, 0, 0, wrow, wcol, l4, l15, acc);
    FENCE("6"); stage_half(Bw, rowB0, cX,      smem + 32768, wid, lane); quad(smem, 1, 0, 1, wrow, wcol, l4, l15, acc);
    FENCE("4"); stage_half(A,  rowA0, cX + 32, smem + 16384, wid, lane); quad(smem, 1, 1, 0, wrow, wcol, l4, l15, acc);
    FENCE("6"); stage_half(Bw, rowB0, cX + 32, smem + 49152, wid, lane); quad(smem, 1, 1, 1, wrow, wcol, l4, l15, acc);
  }
  // final iter j=7: tiles 14 (X), 15 (Y); no further staging after ph3
  {
    const int cY = 15 * 64;
    FENCE("4"); stage_half(A,  rowA0, cY,      smem + 65536 + 0,     wid, lane); quad(smem, 0, 0, 0, wrow, wcol, l4, l15, acc);
    FENCE("6"); stage_half(Bw, rowB0, cY,      smem + 65536 + 32768, wid, lane); quad(smem, 0, 0, 1, wrow, wcol, l4, l15, acc);
    FENCE("4"); stage_half(A,  rowA0, cY + 32, smem + 65536 + 16384, wid, lane); quad(smem, 0, 1, 0, wrow, wcol, l4, l15, acc);
    FENCE("6"); stage_half(Bw, rowB0, cY + 32, smem + 65536 + 49152, wid, lane); quad(smem, 0, 1, 1, wrow, wcol, l4, l15, acc);
    FENCE("4"); quad(smem, 1, 0, 0, wrow, wcol, l4, l15, acc);
    FENCE("4"); quad(smem, 1, 0, 1, wrow, wcol, l4, l15, acc);
    FENCE("0"); quad(smem, 1, 1, 0, wrow, wcol, l4, l15, acc);
    FENCE("0"); quad(smem, 1, 1, 1, wrow, wcol, l4, l15, acc);
  }

#pragma unroll
  for (int m = 0; m < 8; ++m)
#pragma unroll
    for (int rg = 0; rg < 4; ++rg) {
      long row = rowA0 + wrow * 128 + m * 16 + l4 * 4 + rg;
      if (row >= MROWS) continue;
#pragma unroll
      for (int n = 0; n < 4; ++n) {
        long col = rowB0 + wcol * 64 + n * 16 + l15;
        Cout[row * 3072 + col] = f2bf(acc[m][n][rg]);
      }
    }
}

// flat f -> (mt, nt): 8-Mtile super-rows (for gemm_out's 65x8 grid)
DEV void map_tiles(int f, int MT, int NT, int& mt, int& nt) {
  int body = (MT & ~7) * NT;
  if (f >= body) { int r = f - body; mt = (MT & ~7) + r / NT; nt = r % NT; }
  else { int sr = f / (8 * NT); int rem = f - sr * 8 * NT; nt = rem >> 3; mt = sr * 8 + (rem & 7); }
}

// ---------------- out-projection GEMM (f32 out + bias), 128^2 m97 structure ----------------
__global__ __launch_bounds__(256) void gemm_out(const u16* __restrict__ A,
    const u16* __restrict__ Bw, float* __restrict__ Cout, const float* __restrict__ bias) {
  __shared__ char smem[32768];
  int mt, nt;
  { int wg = blockIdx.x; int f = (wg & 7) * 65 + (wg >> 3); map_tiles(f, 65, 8, mt, nt); }
  const int t = threadIdx.x;
  const int wid = t >> 6, lane = t & 63;
  const int l4 = lane >> 4, l15 = lane & 15;
  const int wr = wid >> 1, wc = wid & 1;
  const long rowA0 = (long)mt * 128;
  const long rowB0 = (long)nt * 128;

  f32x4 acc[4][4];
#pragma unroll
  for (int m = 0; m < 4; ++m)
#pragma unroll
    for (int n = 0; n < 4; ++n) { f32x4 z = {0.f,0.f,0.f,0.f}; acc[m][n] = z; }

  const int srow = t >> 3;
  const int scol = (t & 7) * 8;

  for (int k0 = 0; k0 < 1024; k0 += 64) {
    __syncthreads();
#pragma unroll
    for (int i = 0; i < 4; ++i) {
      const u16* ga = A  + (rowA0 + i * 32 + srow) * 1024 + k0 + scol;
      gload_lds16(ga, smem + i * 4096 + wid * 1024);
      const u16* gb = Bw + (rowB0 + i * 32 + srow) * 1024 + k0 + scol;
      gload_lds16(gb, smem + 16384 + i * 4096 + wid * 1024);
    }
    __syncthreads();

    bf16x8 af[4][2], bfr[4][2];
#pragma unroll
    for (int m = 0; m < 4; ++m)
#pragma unroll
      for (int kk = 0; kk < 2; ++kk)
        af[m][kk] = *(const bf16x8*)(smem + (wr * 64 + m * 16 + l15) * 128 + kk * 64 + l4 * 16);
#pragma unroll
    for (int n = 0; n < 4; ++n)
#pragma unroll
      for (int kk = 0; kk < 2; ++kk)
        bfr[n][kk] = *(const bf16x8*)(smem + 16384 + (wc * 64 + n * 16 + l15) * 128 + kk * 64 + l4 * 16);

#pragma unroll
    for (int m = 0; m < 4; ++m)
#pragma unroll
      for (int n = 0; n < 4; ++n)
#pragma unroll
        for (int kk = 0; kk < 2; ++kk)
          acc[m][n] = mfma16(af[m][kk], bfr[n][kk], acc[m][n]);
  }

#pragma unroll
  for (int m = 0; m < 4; ++m)
#pragma unroll
    for (int rg = 0; rg < 4; ++rg) {
      long row = rowA0 + wr * 64 + m * 16 + l4 * 4 + rg;
      if (row >= MROWS) continue;
#pragma unroll
      for (int n = 0; n < 4; ++n) {
        long col = rowB0 + wc * 64 + n * 16 + l15;
        Cout[row * 1024 + col] = acc[m][n][rg] + bias[col];
      }
    }
}

// ---------------- merged post-QKV: rope+head-split (Q,K) | V bias+transpose ----------------
__global__ void postqkv_kernel(const u16* __restrict__ cq, const float* __restrict__ qb,
                               const float* __restrict__ vb,
                               const float* __restrict__ cost, const float* __restrict__ sint,
                               u16* __restrict__ Qh, u16* __restrict__ Kh,
                               u16* __restrict__ VTh) {
  __shared__ float tile[64][65];
  const int blk = blockIdx.x, tid = threadIdx.x;
  if (blk < 513) {
    int idx = blk * 256 + tid;
    if (idx >= MROWS * NHEAD) return;
    int h = idx & 15, row = idx >> 4;
    int b = row / SEQ, n = row - b * SEQ;
    const u16* src = cq + (size_t)row * 3072 + h * 64;
    size_t dq = ((size_t)(b * 16 + h) * SEQ   + n) * 64;
    size_t dk = ((size_t)(b * 16 + h) * KROWS + n) * 64;
    bool dorope = (n > 0);
    const float* ct = cost + (size_t)(n - 1) * 32;
    const float* st = sint + (size_t)(n - 1) * 32;
#pragma unroll
    for (int i = 0; i < 4; ++i) {
      short8 qlo = *(const short8*)(src + i * 8);
      short8 qhi = *(const short8*)(src + 32 + i * 8);
      short8 klo = *(const short8*)(src + 1024 + i * 8);
      short8 khi = *(const short8*)(src + 1024 + 32 + i * 8);
      short8 oqlo, oqhi, oklo, okhi;
#pragma unroll
      for (int j = 0; j < 8; ++j) {
        int d = i * 8 + j;
        float q1 = bf2f((u16)qlo[j]) + qb[h * 64 + d];
        float q2 = bf2f((u16)qhi[j]) + qb[h * 64 + 32 + d];
        float k1 = bf2f((u16)klo[j]);
        float k2 = bf2f((u16)khi[j]);
        float c = dorope ? ct[d] : 1.0f;
        float s = dorope ? st[d] : 0.0f;
        oqlo[j] = (short)f2bf((q1 * c - q2 * s) * QSCALE);
        oqhi[j] = (short)f2bf((q1 * s + q2 * c) * QSCALE);
        oklo[j] = (short)f2bf(k1 * c - k2 * s);
        okhi[j] = (short)f2bf(k1 * s + k2 * c);
      }
      *(short8*)(Qh + dq + i * 8)      = oqlo;
      *(short8*)(Qh + dq + 32 + i * 8) = oqhi;
      *(short8*)(Kh + dk + i * 8)      = oklo;
      *(short8*)(Kh + dk + 32 + i * 8) = okhi;
    }
  } else {
    int wg = blk - 513;
    int bh = wg / 18, nx = wg - bh * 18;
    int b = bh >> 4, h = bh & 15;
    int n0 = nx * 64;
    int c = tid & 63, rq = tid >> 6;
#pragma unroll
    for (int p = 0; p < 16; ++p) {
      int r = p * 4 + rq;
      int n = n0 + r;
      float v = 0.f;
      if (n < SEQ) v = bf2f(cq[(size_t)(b * SEQ + n) * 3072 + 2048 + h * 64 + c]) + vb[h * 64 + c];
      tile[r][c] = v;
    }
    __syncthreads();
#pragma unroll
    for (int p = 0; p < 16; ++p) {
      int d = p * 4 + rq;
      VTh[((size_t)bh * 64 + d) * VPAD + n0 + c] = f2bf(tile[c][d]);
    }
  }
}

// ---------------- flash attention: round-6 proven structure (dbuf, online max) ----------------
DEV void stage_rows(const u16* __restrict__ g, size_t strideElems, char* lbase,
                    int wid, int lane) {
#pragma unroll
  for (int s = 0; s < 2; ++s) {
    int off = s * 4096 + wid * 1024 + lane * 16;
    int r = off >> 7, cs = (off >> 4) & 7;
    const u16* src = g + (size_t)r * strideElems + ((cs ^ (r & 7)) << 3);
    gload_lds16(src, lbase + s * 4096 + wid * 1024);
  }
}

__global__ __launch_bounds__(256, 4) void attn128(const u16* __restrict__ Qh,
    const u16* __restrict__ Kh, const u16* __restrict__ VTh,
    u16* __restrict__ xattn) {
  __shared__ char lds[32768];  // K dbuf 16K | V dbuf 16K
  const int wg = blockIdx.x;
  const int x = (wg & 7) * 144 + (wg >> 3);
  const int qt = x % 9, bh = x / 9;
  const int b = bh >> 4, h = bh & 15;
  const int t = threadIdx.x, w = t >> 6, lane = t & 63;
  const int l4 = lane >> 4, l15 = lane & 15;
  const u16* Qb = Qh + (size_t)bh * (SEQ * 64);
  const u16* Kb = Kh + (size_t)bh * (KROWS * 64);
  const u16* Vb = VTh + (size_t)bh * (64 * VPAD);
  const int q0 = qt * 128 + w * 32;
  const int srcb = l15 + ((l4 & 1) << 5);
  const bool hi4 = (l4 >> 1) != 0;

  bf16x8 aq[2][2];
#pragma unroll
  for (int m = 0; m < 2; ++m) {
    int qr = q0 + m * 16 + l15; if (qr > SEQ - 1) qr = SEQ - 1;
    aq[m][0] = *(const bf16x8*)(Qb + (size_t)qr * 64 + l4 * 8);
    aq[m][1] = *(const bf16x8*)(Qb + (size_t)qr * 64 + 32 + l4 * 8);
  }
  bf16x8 ones;
  { union { unsigned u[4]; bf16x8 v; } ou;
    ou.u[0] = ou.u[1] = ou.u[2] = ou.u[3] = 0x3F803F80u; ones = ou.v; }

  f32x4 o[2][4], osum[2];
  float mrow[2];
#pragma unroll
  for (int m = 0; m < 2; ++m) {
#pragma unroll
    for (int n = 0; n < 4; ++n) { f32x4 z = {0.f,0.f,0.f,0.f}; o[m][n] = z; }
    f32x4 z = {0.f,0.f,0.f,0.f}; osum[m] = z;
    mrow[m] = -1e30f;
  }

  stage_rows(Kb, 64, lds, w, lane);
  stage_rows(Vb, VPAD, lds + 16384, w, lane);
  asm volatile("s_waitcnt vmcnt(0)" ::: "memory");
  __syncthreads();

  int cur = 0;
  for (int kt = 0; kt < 17; ++kt) {
    const int kb = kt * 64;
    if (kt < 16) {
      stage_rows(Kb + (size_t)(kb + 64) * 64, 64, lds + (cur ^ 1) * 8192, w, lane);
      stage_rows(Vb + (kb + 64), VPAD, lds + 16384 + (cur ^ 1) * 8192, w, lane);
    }
    const char* Kl = lds + cur * 8192;
    const char* Vl = lds + 16384 + cur * 8192;

    f32x4 s[2][4];
#pragma unroll
    for (int tt = 0; tt < 4; ++tt) {
      const int kr = tt * 16 + l15;
      const char* kp = Kl + kr * 128;
      bf16x8 bk0 = *(const bf16x8*)(kp + ((l4       ^ (kr & 7)) << 4));
      bf16x8 bk1 = *(const bf16x8*)(kp + (((4 + l4) ^ (kr & 7)) << 4));
#pragma unroll
      for (int m = 0; m < 2; ++m) {
        f32x4 z = {0.f,0.f,0.f,0.f};
        z = mfma16(bk0, aq[m][0], z);
        z = mfma16(bk1, aq[m][1], z);
        s[m][tt] = z;
      }
    }

    if (kt == 16) {
#pragma unroll
      for (int m = 0; m < 2; ++m) {
        s[m][0][0] = (l4 == 0) ? s[m][0][0] : -1e30f;
        s[m][0][1] = -1e30f; s[m][0][2] = -1e30f; s[m][0][3] = -1e30f;
#pragma unroll
        for (int tt = 1; tt < 4; ++tt) {
          s[m][tt][0] = -1e30f; s[m][tt][1] = -1e30f; s[m][tt][2] = -1e30f; s[m][tt][3] = -1e30f;
        }
      }
    }

    float tmax[2];
#pragma unroll
    for (int m = 0; m < 2; ++m) {
      float a0 = fmaxf(fmaxf(s[m][0][0], s[m][0][1]), fmaxf(s[m][0][2], s[m][0][3]));
      float a1 = fmaxf(fmaxf(s[m][1][0], s[m][1][1]), fmaxf(s[m][1][2], s[m][1][3]));
      float a2 = fmaxf(fmaxf(s[m][2][0], s[m][2][1]), fmaxf(s[m][2][2], s[m][2][3]));
      float a3 = fmaxf(fmaxf(s[m][3][0], s[m][3][1]), fmaxf(s[m][3][2], s[m][3][3]));
      float tm = fmaxf(fmaxf(a0, a1), fmaxf(a2, a3));
      tm = fmaxf(tm, __shfl_xor(tm, 16));
      tm = fmaxf(tm, __shfl_xor(tm, 32));
      tmax[m] = tm;
    }

    int needR = (tmax[0] > mrow[0] + 8.0f) || (tmax[1] > mrow[1] + 8.0f);
    if (__any(needR)) {
#pragma unroll
      for (int m = 0; m < 2; ++m) {
        float mnew = fmaxf(mrow[m], tmax[m]);
        float alpha = exp2_fast(mrow[m] - mnew);
        mrow[m] = mnew;
        float al[4];
#pragma unroll
        for (int rg = 0; rg < 4; ++rg) al[rg] = __shfl(alpha, l4 * 4 + rg);
#pragma unroll
        for (int n = 0; n < 4; ++n)
#pragma unroll
          for (int rg = 0; rg < 4; ++rg) o[m][n][rg] *= al[rg];
#pragma unroll
        for (int rg = 0; rg < 4; ++rg) osum[m][rg] *= al[rg];
      }
    }

    unsigned pk[2][4][2];
#pragma unroll
    for (int m = 0; m < 2; ++m)
#pragma unroll
      for (int tt = 0; tt < 4; ++tt) {
        float p0 = exp2_fast(s[m][tt][0] - mrow[m]);
        float p1 = exp2_fast(s[m][tt][1] - mrow[m]);
        float p2 = exp2_fast(s[m][tt][2] - mrow[m]);
        float p3 = exp2_fast(s[m][tt][3] - mrow[m]);
        pk[m][tt][0] = cvt_pk_bf16(p0, p1);
        pk[m][tt][1] = cvt_pk_bf16(p2, p3);
      }

#pragma unroll
    for (int kk = 0; kk < 2; ++kk) {
      bf16x8 pa[2];
#pragma unroll
      for (int m = 0; m < 2; ++m) {
        union { unsigned u[4]; bf16x8 v; } pu;
#pragma unroll
        for (int bb = 0; bb < 2; ++bb)
#pragma unroll
          for (int pr = 0; pr < 2; ++pr) {
            unsigned t0 = (unsigned)__shfl((int)pk[m][2 * kk][pr],     srcb + bb * 16);
            unsigned t1 = (unsigned)__shfl((int)pk[m][2 * kk + 1][pr], srcb + bb * 16);
            pu.u[bb * 2 + pr] = hi4 ? t1 : t0;
          }
        pa[m] = pu.v;
      }
#pragma unroll
      for (int n = 0; n < 4; ++n) {
        const int vr = n * 16 + l15;
        bf16x8 bv = *(const bf16x8*)(Vl + vr * 128 + (((kk * 4 + l4) ^ (vr & 7)) << 4));
#pragma unroll
        for (int m = 0; m < 2; ++m)
          o[m][n] = mfma16(pa[m], bv, o[m][n]);
      }
#pragma unroll
      for (int m = 0; m < 2; ++m)
        osum[m] = mfma16(pa[m], ones, osum[m]);
    }

    asm volatile("s_waitcnt vmcnt(0)" ::: "memory");
    __syncthreads();
    cur ^= 1;
  }

#pragma unroll
  for (int m = 0; m < 2; ++m)
#pragma unroll
    for (int n = 0; n < 4; ++n)
#pragma unroll
      for (int rg = 0; rg < 4; ++rg) {
        int qrow = q0 + m * 16 + l4 * 4 + rg;
        if (qrow < SEQ)
          xattn[(size_t)(b * SEQ + qrow) * 1024 + h * 64 + n * 16 + l15] =
              f2bf(o[m][n][rg] / osum[m][rg]);
      }
}

// ---------------- launch ----------------

extern "C" void kernel_launch(void* const* d_in, const int* in_sizes, int n_in,
                              void* d_out, int out_size, void* d_ws, size_t ws_size,
                              hipStream_t stream) {
  const float* x      = (const float*)d_in[0];
  const float* wq     = (const float*)d_in[1];
  const float* wk     = (const float*)d_in[2];
  const float* wv     = (const float*)d_in[3];
  const float* q_bias = (const float*)d_in[4];
  const float* v_bias = (const float*)d_in[5];
  const float* w_out  = (const float*)d_in[6];
  const float* b_out  = (const float*)d_in[7];

  char* ws = (char*)d_ws;
  size_t off = 0;
  auto alc = [&](size_t bytes) { size_t r = off; off += (bytes + 255) & ~(size_t)255; return r; };

  u16*  x_bf  = (u16*)(ws + alc((size_t)MROWS * 1024 * 2));
  u16*  wtqkv = (u16*)(ws + alc((size_t)3072 * 1024 * 2));
  u16*  wtout = (u16*)(ws + alc((size_t)1024 * 1024 * 2));
  u16*  xattn = (u16*)(ws + alc((size_t)MROWS * 1024 * 2));
  u16*  cqkv  = (u16*)(ws + alc((size_t)8448 * 3072 * 2));   // padded to 33*256 rows
  u16*  Qhp   = (u16*)(ws + alc((size_t)128 * SEQ * 64 * 2));
  u16*  Khp   = (u16*)(ws + alc((size_t)128 * KROWS * 64 * 2));
  u16*  VThp  = (u16*)(ws + alc((size_t)128 * 64 * VPAD * 2));
  float* cost = (float*)(ws + alc((size_t)1024 * 32 * 4));
  float* sint = (float*)(ws + alc((size_t)1024 * 32 * 4));
  (void)ws_size; (void)in_sizes; (void)n_in; (void)out_size;

  // 1. merged prep: cast x | transpose weights | rope tables
  prep_kernel<<<dim3(5252), 256, 0, stream>>>(x, wq, wk, wv, w_out,
                                              x_bf, wtqkv, wtout, cost, sint);
  // 2. fused QKV projection: 256^2 tiles, 8-phase schedule
  gemm256<<<dim3(396), 512, 0, stream>>>(x_bf, wtqkv, cqkv);
  // 3. merged post-QKV: rope+head-split (Q,K) | V bias+transpose
  postqkv_kernel<<<dim3(513 + 2304), 256, 0, stream>>>(cqkv, q_bias, v_bias,
                                                       cost, sint, Qhp, Khp, VThp);
  // 4. flash attention (XCD-swizzled 1D grid: 9 q-tiles x 128 bh)
  attn128<<<dim3(1152), 256, 0, stream>>>(Qhp, Khp, VThp, xattn);
  // 5. output projection + bias -> d_out (fp32)
  gemm_out<<<dim3(520), 256, 0, stream>>>(xattn, wtout, (float*)d_out, b_out);
}

// Round 15
// 236.329 us; speedup vs baseline: 1.1051x; 1.0465x over previous
//
#include <hip/hip_runtime.h>

typedef unsigned short u16;
typedef __attribute__((ext_vector_type(8))) short  short8;
typedef __attribute__((ext_vector_type(8))) __bf16 bf16x8;
typedef __attribute__((ext_vector_type(4))) __bf16 bf16x4;
typedef __attribute__((ext_vector_type(4))) float  f32x4;

#define DEV __device__ __forceinline__

// B=8, N=1025, D=1024, H=16, Dh=64
#define BATCH 8
#define SEQ   1025
#define DMODEL 1024
#define NHEAD 16
#define DH    64
#define MROWS (BATCH*SEQ)      // 8200
#define VPAD  1152             // key padding for VT
#define KROWS 1088             // padded K row stride (17*64)

DEV float bf2f(u16 u) { union { unsigned int i; float f; } v; v.i = ((unsigned int)u) << 16; return v.f; }
DEV u16 f2bf(float f) {
  union { float f; unsigned int i; } v; v.f = f;
  unsigned int x = v.i;
  return (u16)((x + 0x7fffu + ((x >> 16) & 1u)) >> 16);  // RNE
}

DEV f32x4 mfma16(bf16x8 a, bf16x8 b, f32x4 c) {
  return __builtin_amdgcn_mfma_f32_16x16x32_bf16(a, b, c, 0, 0, 0);
}

DEV void gload_lds16(const void* g, void* s) {
  __builtin_amdgcn_global_load_lds(
      (const __attribute__((address_space(1))) void*)g,
      (__attribute__((address_space(3))) void*)s, 16, 0, 0);
}

DEV float exp2_fast(float x) { float r; asm("v_exp_f32 %0, %1" : "=v"(r) : "v"(x)); return r; }
DEV unsigned cvt_pk_bf16(float lo, float hi) {
  unsigned r;
  asm("v_cvt_pk_bf16_f32 %0, %1, %2" : "=v"(r) : "v"(lo), "v"(hi));
  return r;
}

#define QSCALE (0.125f * 1.44269504088896341f)

// ---------------- merged prep: cast_x | weight transpose | rope tables ----------------
__global__ void prep_kernel(const float* __restrict__ x,
                            const float* __restrict__ wq, const float* __restrict__ wk,
                            const float* __restrict__ wv, const float* __restrict__ wo,
                            u16* __restrict__ x_bf, u16* __restrict__ wtqkv,
                            u16* __restrict__ wtout,
                            float* __restrict__ cost, float* __restrict__ sint) {
  __shared__ float tile[64][65];
  const int blk = blockIdx.x, tid = threadIdx.x;
  if (blk < 4100) {
    int i = blk * 256 + tid;
    if (i >= MROWS * 1024 / 8) return;
    const float4* p = (const float4*)x + (size_t)i * 2;
    float4 a = p[0], b = p[1];
    short8 o;
    o[0] = (short)f2bf(a.x); o[1] = (short)f2bf(a.y); o[2] = (short)f2bf(a.z); o[3] = (short)f2bf(a.w);
    o[4] = (short)f2bf(b.x); o[5] = (short)f2bf(b.y); o[6] = (short)f2bf(b.z); o[7] = (short)f2bf(b.w);
    *(short8*)(x_bf + (size_t)i * 8) = o;
  } else if (blk < 5124) {
    int wg = blk - 4100;
    int z = wg >> 8, rem = wg & 255;
    int kx = rem & 15, ny = rem >> 4;
    const float* src = (z == 0) ? wq : (z == 1) ? wk : (z == 2) ? wv : wo;
    int k0 = kx * 64, n0 = ny * 64;
    int c = tid & 63, rq = tid >> 6;
#pragma unroll
    for (int p = 0; p < 16; ++p) {
      int r = p * 4 + rq;
      tile[r][c] = src[(size_t)(k0 + r) * 1024 + n0 + c];
    }
    __syncthreads();
    u16* dst = (z < 3) ? (wtqkv + (size_t)z * 1024 * 1024) : wtout;
#pragma unroll
    for (int p = 0; p < 16; ++p) {
      int r = p * 4 + rq;
      dst[(size_t)(n0 + r) * 1024 + k0 + c] = f2bf(tile[c][r]);
    }
  } else {
    int i = (blk - 5124) * 256 + tid;
    if (i >= 1024 * 32) return;
    int pos = i >> 5, d = i & 31;
    float inv = powf(10000.0f, -(float)d / 32.0f);
    float ang = (float)pos * inv;
    cost[i] = cosf(ang);
    sint[i] = sinf(ang);
  }
}

// ---------------- 256x256 bf16 GEMM, 8-phase schedule (T2+T3+T4+T5) ----------------
#define FENCE(N) asm volatile("s_waitcnt vmcnt(" N ") lgkmcnt(0)\n\ts_barrier" ::: "memory")

DEV void stage_half(const u16* __restrict__ gpanel, long row0, int kcol,
                    char* dst, int wid, int lane) {
#pragma unroll
  for (int s = 0; s < 2; ++s) {
    int tt = wid * 64 + lane;
    int row = s * 128 + (tt >> 2), c2 = tt & 3;
    const u16* src = gpanel + (row0 + row) * 1024 + kcol + ((c2 ^ ((row >> 1) & 3)) << 3);
    gload_lds16(src, dst + s * 8192 + wid * 1024);
  }
}

DEV void quad(const char* sm, int buf, int kk, int mh, int wrow, int wcol,
              int l4, int l15, f32x4 (&acc)[8][4]) {
  const char* Ab = sm + buf * 65536 + kk * 16384;
  const char* Bb = sm + buf * 65536 + 32768 + kk * 16384;
  bf16x8 bfr[4];
#pragma unroll
  for (int n = 0; n < 4; ++n) {
    int r = wcol * 64 + n * 16 + l15;
    bfr[n] = *(const bf16x8*)(Bb + r * 64 + ((l4 << 4) ^ (((r >> 1) & 3) << 4)));
  }
  bf16x8 af[4];
#pragma unroll
  for (int m = 0; m < 4; ++m) {
    int r = wrow * 128 + (mh * 4 + m) * 16 + l15;
    af[m] = *(const bf16x8*)(Ab + r * 64 + ((l4 << 4) ^ (((r >> 1) & 3) << 4)));
  }
  __builtin_amdgcn_s_setprio(1);
#pragma unroll
  for (int m = 0; m < 4; ++m)
#pragma unroll
    for (int n = 0; n < 4; ++n)
      acc[mh * 4 + m][n] = mfma16(af[m], bfr[n], acc[mh * 4 + m][n]);
  __builtin_amdgcn_s_setprio(0);
}

__global__ __launch_bounds__(512, 2) void gemm256(const u16* __restrict__ A,
    const u16* __restrict__ Bw, u16* __restrict__ Cout) {
  __shared__ char smem[131072];   // X: A-k0|A-k1|B-k0|B-k1 (16KB each); Y at +65536
  int mt, nt;
  {
    int orig = blockIdx.x;
    int xcd = orig & 7;
    int f = (xcd < 4 ? xcd * 50 : 200 + (xcd - 4) * 49) + (orig >> 3);
    if (f < 384) { int sr = f / 48, rem = f % 48; nt = rem >> 2; mt = sr * 4 + (rem & 3); }
    else { mt = 32; nt = f - 384; }
  }
  const int t = threadIdx.x;
  const int wid = t >> 6, lane = t & 63;
  const int l4 = lane >> 4, l15 = lane & 15;
  const int wrow = wid >> 2, wcol = wid & 3;    // 2M x 4N waves
  const long rowA0 = (long)mt * 256;
  const long rowB0 = (long)nt * 256;

  f32x4 acc[8][4];
#pragma unroll
  for (int m = 0; m < 8; ++m)
#pragma unroll
    for (int n = 0; n < 4; ++n) { f32x4 z = {0.f,0.f,0.f,0.f}; acc[m][n] = z; }

  stage_half(A,  rowA0, 0,  smem + 0,     wid, lane);
  stage_half(Bw, rowB0, 0,  smem + 32768, wid, lane);
  stage_half(A,  rowA0, 32, smem + 16384, wid, lane);
  stage_half(Bw, rowB0, 32, smem + 49152, wid, lane);

  for (int j = 0; j < 7; ++j) {
    const int cY = (2 * j + 1) * 64, cX = (2 * j + 2) * 64;
    FENCE("4"); stage_half(A,  rowA0, cY,      smem + 65536 + 0,     wid, lane); quad(smem, 0, 0, 0, wrow, wcol, l4, l15, acc);
    FENCE("6"); stage_half(Bw, rowB0, cY,      smem + 65536 + 32768, wid, lane); quad(smem, 0, 0, 1, wrow, wcol, l4, l15, acc);
    FENCE("4"); stage_half(A,  rowA0, cY + 32, smem + 65536 + 16384, wid, lane); quad(smem, 0, 1, 0, wrow, wcol, l4, l15, acc);
    FENCE("6"); stage_half(Bw, rowB0, cY + 32, smem + 65536 + 49152, wid, lane); quad(smem, 0, 1, 1, wrow, wcol, l4, l15, acc);
    FENCE("4"); stage_half(A,  rowA0, cX,      smem + 0,     wid, lane); quad(smem, 1, 0, 0, wrow, wcol, l4, l15, acc);
    FENCE("6"); stage_half(Bw, rowB0, cX,      smem + 32768, wid, lane); quad(smem, 1, 0, 1, wrow, wcol, l4, l15, acc);
    FENCE("4"); stage_half(A,  rowA0, cX + 32, smem + 16384, wid, lane); quad(smem, 1, 1, 0, wrow, wcol, l4, l15, acc);
    FENCE("6"); stage_half(Bw, rowB0, cX + 32, smem + 49152, wid, lane); quad(smem, 1, 1, 1, wrow, wcol, l4, l15, acc);
  }
  {
    const int cY = 15 * 64;
    FENCE("4"); stage_half(A,  rowA0, cY,      smem + 65536 + 0,     wid, lane); quad(smem, 0, 0, 0, wrow, wcol, l4, l15, acc);
    FENCE("6"); stage_half(Bw, rowB0, cY,      smem + 65536 + 32768, wid, lane); quad(smem, 0, 0, 1, wrow, wcol, l4, l15, acc);
    FENCE("4"); stage_half(A,  rowA0, cY + 32, smem + 65536 + 16384, wid, lane); quad(smem, 0, 1, 0, wrow, wcol, l4, l15, acc);
    FENCE("6"); stage_half(Bw, rowB0, cY + 32, smem + 65536 + 49152, wid, lane); quad(smem, 0, 1, 1, wrow, wcol, l4, l15, acc);
    FENCE("4"); quad(smem, 1, 0, 0, wrow, wcol, l4, l15, acc);
    FENCE("4"); quad(smem, 1, 0, 1, wrow, wcol, l4, l15, acc);
    FENCE("0"); quad(smem, 1, 1, 0, wrow, wcol, l4, l15, acc);
    FENCE("0"); quad(smem, 1, 1, 1, wrow, wcol, l4, l15, acc);
  }

#pragma unroll
  for (int m = 0; m < 8; ++m)
#pragma unroll
    for (int rg = 0; rg < 4; ++rg) {
      long row = rowA0 + wrow * 128 + m * 16 + l4 * 4 + rg;
      if (row >= MROWS) continue;
#pragma unroll
      for (int n = 0; n < 4; ++n) {
        long col = rowB0 + wcol * 64 + n * 16 + l15;
        Cout[row * 3072 + col] = f2bf(acc[m][n][rg]);
      }
    }
}

// flat f -> (mt, nt): 8-Mtile super-rows (for gemm_out's 65x8 grid)
DEV void map_tiles(int f, int MT, int NT, int& mt, int& nt) {
  int body = (MT & ~7) * NT;
  if (f >= body) { int r = f - body; mt = (MT & ~7) + r / NT; nt = r % NT; }
  else { int sr = f / (8 * NT); int rem = f - sr * 8 * NT; nt = rem >> 3; mt = sr * 8 + (rem & 7); }
}

// ---------------- out-projection GEMM (f32 out + bias), 128^2 m97 structure ----------------
__global__ __launch_bounds__(256) void gemm_out(const u16* __restrict__ A,
    const u16* __restrict__ Bw, float* __restrict__ Cout, const float* __restrict__ bias) {
  __shared__ char smem[32768];
  int mt, nt;
  { int wg = blockIdx.x; int f = (wg & 7) * 65 + (wg >> 3); map_tiles(f, 65, 8, mt, nt); }
  const int t = threadIdx.x;
  const int wid = t >> 6, lane = t & 63;
  const int l4 = lane >> 4, l15 = lane & 15;
  const int wr = wid >> 1, wc = wid & 1;
  const long rowA0 = (long)mt * 128;
  const long rowB0 = (long)nt * 128;

  f32x4 acc[4][4];
#pragma unroll
  for (int m = 0; m < 4; ++m)
#pragma unroll
    for (int n = 0; n < 4; ++n) { f32x4 z = {0.f,0.f,0.f,0.f}; acc[m][n] = z; }

  const int srow = t >> 3;
  const int scol = (t & 7) * 8;

  for (int k0 = 0; k0 < 1024; k0 += 64) {
    __syncthreads();
#pragma unroll
    for (int i = 0; i < 4; ++i) {
      const u16* ga = A  + (rowA0 + i * 32 + srow) * 1024 + k0 + scol;
      gload_lds16(ga, smem + i * 4096 + wid * 1024);
      const u16* gb = Bw + (rowB0 + i * 32 + srow) * 1024 + k0 + scol;
      gload_lds16(gb, smem + 16384 + i * 4096 + wid * 1024);
    }
    __syncthreads();

    bf16x8 af[4][2], bfr[4][2];
#pragma unroll
    for (int m = 0; m < 4; ++m)
#pragma unroll
      for (int kk = 0; kk < 2; ++kk)
        af[m][kk] = *(const bf16x8*)(smem + (wr * 64 + m * 16 + l15) * 128 + kk * 64 + l4 * 16);
#pragma unroll
    for (int n = 0; n < 4; ++n)
#pragma unroll
      for (int kk = 0; kk < 2; ++kk)
        bfr[n][kk] = *(const bf16x8*)(smem + 16384 + (wc * 64 + n * 16 + l15) * 128 + kk * 64 + l4 * 16);

#pragma unroll
    for (int m = 0; m < 4; ++m)
#pragma unroll
      for (int n = 0; n < 4; ++n)
#pragma unroll
        for (int kk = 0; kk < 2; ++kk)
          acc[m][n] = mfma16(af[m][kk], bfr[n][kk], acc[m][n]);
  }

#pragma unroll
  for (int m = 0; m < 4; ++m)
#pragma unroll
    for (int rg = 0; rg < 4; ++rg) {
      long row = rowA0 + wr * 64 + m * 16 + l4 * 4 + rg;
      if (row >= MROWS) continue;
#pragma unroll
      for (int n = 0; n < 4; ++n) {
        long col = rowB0 + wc * 64 + n * 16 + l15;
        Cout[row * 1024 + col] = acc[m][n][rg] + bias[col];
      }
    }
}

// ---------------- merged post-QKV: rope+head-split (Q,K) | V bias+transpose ----------------
__global__ void postqkv_kernel(const u16* __restrict__ cq, const float* __restrict__ qb,
                               const float* __restrict__ vb,
                               const float* __restrict__ cost, const float* __restrict__ sint,
                               u16* __restrict__ Qh, u16* __restrict__ Kh,
                               u16* __restrict__ VTh) {
  __shared__ float tile[64][65];
  const int blk = blockIdx.x, tid = threadIdx.x;
  if (blk < 513) {
    int idx = blk * 256 + tid;
    if (idx >= MROWS * NHEAD) return;
    int h = idx & 15, row = idx >> 4;
    int b = row / SEQ, n = row - b * SEQ;
    const u16* src = cq + (size_t)row * 3072 + h * 64;
    size_t dq = ((size_t)(b * 16 + h) * SEQ   + n) * 64;
    size_t dk = ((size_t)(b * 16 + h) * KROWS + n) * 64;
    bool dorope = (n > 0);
    const float* ct = cost + (size_t)(n - 1) * 32;
    const float* st = sint + (size_t)(n - 1) * 32;
#pragma unroll
    for (int i = 0; i < 4; ++i) {
      short8 qlo = *(const short8*)(src + i * 8);
      short8 qhi = *(const short8*)(src + 32 + i * 8);
      short8 klo = *(const short8*)(src + 1024 + i * 8);
      short8 khi = *(const short8*)(src + 1024 + 32 + i * 8);
      short8 oqlo, oqhi, oklo, okhi;
#pragma unroll
      for (int j = 0; j < 8; ++j) {
        int d = i * 8 + j;
        float q1 = bf2f((u16)qlo[j]) + qb[h * 64 + d];
        float q2 = bf2f((u16)qhi[j]) + qb[h * 64 + 32 + d];
        float k1 = bf2f((u16)klo[j]);
        float k2 = bf2f((u16)khi[j]);
        float c = dorope ? ct[d] : 1.0f;
        float s = dorope ? st[d] : 0.0f;
        oqlo[j] = (short)f2bf((q1 * c - q2 * s) * QSCALE);
        oqhi[j] = (short)f2bf((q1 * s + q2 * c) * QSCALE);
        oklo[j] = (short)f2bf(k1 * c - k2 * s);
        okhi[j] = (short)f2bf(k1 * s + k2 * c);
      }
      *(short8*)(Qh + dq + i * 8)      = oqlo;
      *(short8*)(Qh + dq + 32 + i * 8) = oqhi;
      *(short8*)(Kh + dk + i * 8)      = oklo;
      *(short8*)(Kh + dk + 32 + i * 8) = okhi;
    }
  } else {
    int wg = blk - 513;
    int bh = wg / 18, nx = wg - bh * 18;
    int b = bh >> 4, h = bh & 15;
    int n0 = nx * 64;
    int c = tid & 63, rq = tid >> 6;
#pragma unroll
    for (int p = 0; p < 16; ++p) {
      int r = p * 4 + rq;
      int n = n0 + r;
      float v = 0.f;
      if (n < SEQ) v = bf2f(cq[(size_t)(b * SEQ + n) * 3072 + 2048 + h * 64 + c]) + vb[h * 64 + c];
      tile[r][c] = v;
    }
    __syncthreads();
#pragma unroll
    for (int p = 0; p < 16; ++p) {
      int d = p * 4 + rq;
      VTh[((size_t)bh * 64 + d) * VPAD + n0 + c] = f2bf(tile[c][d]);
    }
  }
}

// ---------------- flash attention: dbuf + online max; zero-shuffle PV ----------------
// PV A-fragment k-slot<->key bijection chosen so each lane's 8 A-elements are its
// OWN P values (register concat of pk words): k-slot (l4,j) -> key =
// (2kk + (j>>2))*16 + l4*4 + (j&3). V B-frags read the matching two 8B chunks.
// This deletes all 16 ds_bpermute/tile (and their bank conflicts).
DEV void stage_rows(const u16* __restrict__ g, size_t strideElems, char* lbase,
                    int wid, int lane) {
#pragma unroll
  for (int s = 0; s < 2; ++s) {
    int off = s * 4096 + wid * 1024 + lane * 16;
    int r = off >> 7, cs = (off >> 4) & 7;
    const u16* src = g + (size_t)r * strideElems + ((cs ^ (r & 7)) << 3);
    gload_lds16(src, lbase + s * 4096 + wid * 1024);
  }
}

__global__ __launch_bounds__(256, 4) void attn128(const u16* __restrict__ Qh,
    const u16* __restrict__ Kh, const u16* __restrict__ VTh,
    u16* __restrict__ xattn) {
  __shared__ char lds[32768];  // K dbuf 16K | V dbuf 16K
  const int wg = blockIdx.x;
  const int x = (wg & 7) * 144 + (wg >> 3);
  const int qt = x % 9, bh = x / 9;
  const int b = bh >> 4, h = bh & 15;
  const int t = threadIdx.x, w = t >> 6, lane = t & 63;
  const int l4 = lane >> 4, l15 = lane & 15;
  const u16* Qb = Qh + (size_t)bh * (SEQ * 64);
  const u16* Kb = Kh + (size_t)bh * (KROWS * 64);
  const u16* Vb = VTh + (size_t)bh * (64 * VPAD);
  const int q0 = qt * 128 + w * 32;

  bf16x8 aq[2][2];
#pragma unroll
  for (int m = 0; m < 2; ++m) {
    int qr = q0 + m * 16 + l15; if (qr > SEQ - 1) qr = SEQ - 1;
    aq[m][0] = *(const bf16x8*)(Qb + (size_t)qr * 64 + l4 * 8);
    aq[m][1] = *(const bf16x8*)(Qb + (size_t)qr * 64 + 32 + l4 * 8);
  }
  bf16x8 ones;
  { union { unsigned u[4]; bf16x8 v; } ou;
    ou.u[0] = ou.u[1] = ou.u[2] = ou.u[3] = 0x3F803F80u; ones = ou.v; }

  f32x4 o[2][4], osum[2];
  float mrow[2];
#pragma unroll
  for (int m = 0; m < 2; ++m) {
#pragma unroll
    for (int n = 0; n < 4; ++n) { f32x4 z = {0.f,0.f,0.f,0.f}; o[m][n] = z; }
    f32x4 z = {0.f,0.f,0.f,0.f}; osum[m] = z;
    mrow[m] = -1e30f;
  }

  stage_rows(Kb, 64, lds, w, lane);
  stage_rows(Vb, VPAD, lds + 16384, w, lane);
  asm volatile("s_waitcnt vmcnt(0)" ::: "memory");
  __syncthreads();

  int cur = 0;
  for (int kt = 0; kt < 17; ++kt) {
    const int kb = kt * 64;
    if (kt < 16) {
      stage_rows(Kb + (size_t)(kb + 64) * 64, 64, lds + (cur ^ 1) * 8192, w, lane);
      stage_rows(Vb + (kb + 64), VPAD, lds + 16384 + (cur ^ 1) * 8192, w, lane);
    }
    const char* Kl = lds + cur * 8192;
    const char* Vl = lds + 16384 + cur * 8192;

    f32x4 s[2][4];
#pragma unroll
    for (int tt = 0; tt < 4; ++tt) {
      const int kr = tt * 16 + l15;
      const char* kp = Kl + kr * 128;
      bf16x8 bk0 = *(const bf16x8*)(kp + ((l4       ^ (kr & 7)) << 4));
      bf16x8 bk1 = *(const bf16x8*)(kp + (((4 + l4) ^ (kr & 7)) << 4));
#pragma unroll
      for (int m = 0; m < 2; ++m) {
        f32x4 z = {0.f,0.f,0.f,0.f};
        z = mfma16(bk0, aq[m][0], z);
        z = mfma16(bk1, aq[m][1], z);
        s[m][tt] = z;
      }
    }

    if (kt == 16) {
#pragma unroll
      for (int m = 0; m < 2; ++m) {
        s[m][0][0] = (l4 == 0) ? s[m][0][0] : -1e30f;
        s[m][0][1] = -1e30f; s[m][0][2] = -1e30f; s[m][0][3] = -1e30f;
#pragma unroll
        for (int tt = 1; tt < 4; ++tt) {
          s[m][tt][0] = -1e30f; s[m][tt][1] = -1e30f; s[m][tt][2] = -1e30f; s[m][tt][3] = -1e30f;
        }
      }
    }

    float tmax[2];
#pragma unroll
    for (int m = 0; m < 2; ++m) {
      float a0 = fmaxf(fmaxf(s[m][0][0], s[m][0][1]), fmaxf(s[m][0][2], s[m][0][3]));
      float a1 = fmaxf(fmaxf(s[m][1][0], s[m][1][1]), fmaxf(s[m][1][2], s[m][1][3]));
      float a2 = fmaxf(fmaxf(s[m][2][0], s[m][2][1]), fmaxf(s[m][2][2], s[m][2][3]));
      float a3 = fmaxf(fmaxf(s[m][3][0], s[m][3][1]), fmaxf(s[m][3][2], s[m][3][3]));
      float tm = fmaxf(fmaxf(a0, a1), fmaxf(a2, a3));
      tm = fmaxf(tm, __shfl_xor(tm, 16));
      tm = fmaxf(tm, __shfl_xor(tm, 32));
      tmax[m] = tm;
    }

    int needR = (tmax[0] > mrow[0] + 8.0f) || (tmax[1] > mrow[1] + 8.0f);
    if (__any(needR)) {
#pragma unroll
      for (int m = 0; m < 2; ++m) {
        float mnew = fmaxf(mrow[m], tmax[m]);
        float alpha = exp2_fast(mrow[m] - mnew);
        mrow[m] = mnew;
        float al[4];
#pragma unroll
        for (int rg = 0; rg < 4; ++rg) al[rg] = __shfl(alpha, l4 * 4 + rg);
#pragma unroll
        for (int n = 0; n < 4; ++n)
#pragma unroll
          for (int rg = 0; rg < 4; ++rg) o[m][n][rg] *= al[rg];
#pragma unroll
        for (int rg = 0; rg < 4; ++rg) osum[m][rg] *= al[rg];
      }
    }

    unsigned pk[2][4][2];
#pragma unroll
    for (int m = 0; m < 2; ++m)
#pragma unroll
      for (int tt = 0; tt < 4; ++tt) {
        float p0 = exp2_fast(s[m][tt][0] - mrow[m]);
        float p1 = exp2_fast(s[m][tt][1] - mrow[m]);
        float p2 = exp2_fast(s[m][tt][2] - mrow[m]);
        float p3 = exp2_fast(s[m][tt][3] - mrow[m]);
        pk[m][tt][0] = cvt_pk_bf16(p0, p1);
        pk[m][tt][1] = cvt_pk_bf16(p2, p3);
      }

#pragma unroll
    for (int kk = 0; kk < 2; ++kk) {
      // pa = lane's own P values (keys (2kk)*16+l4*4+0..3, (2kk+1)*16+l4*4+0..3)
      bf16x8 pa[2];
#pragma unroll
      for (int m = 0; m < 2; ++m) {
        union { unsigned u[4]; bf16x8 v; } pu;
        pu.u[0] = pk[m][2 * kk][0];
        pu.u[1] = pk[m][2 * kk][1];
        pu.u[2] = pk[m][2 * kk + 1][0];
        pu.u[3] = pk[m][2 * kk + 1][1];
        pa[m] = pu.v;
      }
      // V B-frags in the SAME key order: two 8B chunks 32B apart, swizzle-aware
      const int inner = (l4 & 1) * 8;
      const int c0 = kk * 4 + (l4 >> 1);
#pragma unroll
      for (int n = 0; n < 4; ++n) {
        const int vr = n * 16 + l15;
        const char* vp = Vl + vr * 128;
        union { bf16x4 h[2]; bf16x8 v; } bu;
        bu.h[0] = *(const bf16x4*)(vp + ((c0 ^ (vr & 7)) << 4) + inner);
        bu.h[1] = *(const bf16x4*)(vp + (((c0 + 2) ^ (vr & 7)) << 4) + inner);
#pragma unroll
        for (int m = 0; m < 2; ++m)
          o[m][n] = mfma16(pa[m], bu.v, o[m][n]);
      }
#pragma unroll
      for (int m = 0; m < 2; ++m)
        osum[m] = mfma16(pa[m], ones, osum[m]);
    }

    asm volatile("s_waitcnt vmcnt(0)" ::: "memory");
    __syncthreads();
    cur ^= 1;
  }

#pragma unroll
  for (int m = 0; m < 2; ++m)
#pragma unroll
    for (int n = 0; n < 4; ++n)
#pragma unroll
      for (int rg = 0; rg < 4; ++rg) {
        int qrow = q0 + m * 16 + l4 * 4 + rg;
        if (qrow < SEQ)
          xattn[(size_t)(b * SEQ + qrow) * 1024 + h * 64 + n * 16 + l15] =
              f2bf(o[m][n][rg] / osum[m][rg]);
      }
}

// ---------------- launch ----------------

extern "C" void kernel_launch(void* const* d_in, const int* in_sizes, int n_in,
                              void* d_out, int out_size, void* d_ws, size_t ws_size,
                              hipStream_t stream) {
  const float* x      = (const float*)d_in[0];
  const float* wq     = (const float*)d_in[1];
  const float* wk     = (const float*)d_in[2];
  const float* wv     = (const float*)d_in[3];
  const float* q_bias = (const float*)d_in[4];
  const float* v_bias = (const float*)d_in[5];
  const float* w_out  = (const float*)d_in[6];
  const float* b_out  = (const float*)d_in[7];

  char* ws = (char*)d_ws;
  size_t off = 0;
  auto alc = [&](size_t bytes) { size_t r = off; off += (bytes + 255) & ~(size_t)255; return r; };

  u16*  x_bf  = (u16*)(ws + alc((size_t)MROWS * 1024 * 2));
  u16*  wtqkv = (u16*)(ws + alc((size_t)3072 * 1024 * 2));
  u16*  wtout = (u16*)(ws + alc((size_t)1024 * 1024 * 2));
  u16*  xattn = (u16*)(ws + alc((size_t)MROWS * 1024 * 2));
  u16*  cqkv  = (u16*)(ws + alc((size_t)8448 * 3072 * 2));   // padded to 33*256 rows
  u16*  Qhp   = (u16*)(ws + alc((size_t)128 * SEQ * 64 * 2));
  u16*  Khp   = (u16*)(ws + alc((size_t)128 * KROWS * 64 * 2));
  u16*  VThp  = (u16*)(ws + alc((size_t)128 * 64 * VPAD * 2));
  float* cost = (float*)(ws + alc((size_t)1024 * 32 * 4));
  float* sint = (float*)(ws + alc((size_t)1024 * 32 * 4));
  (void)ws_size; (void)in_sizes; (void)n_in; (void)out_size;

  // 1. merged prep: cast x | transpose weights | rope tables
  prep_kernel<<<dim3(5252), 256, 0, stream>>>(x, wq, wk, wv, w_out,
                                              x_bf, wtqkv, wtout, cost, sint);
  // 2. fused QKV projection: 256^2 tiles, 8-phase schedule
  gemm256<<<dim3(396), 512, 0, stream>>>(x_bf, wtqkv, cqkv);
  // 3. merged post-QKV: rope+head-split (Q,K) | V bias+transpose
  postqkv_kernel<<<dim3(513 + 2304), 256, 0, stream>>>(cqkv, q_bias, v_bias,
                                                       cost, sint, Qhp, Khp, VThp);
  // 4. flash attention (XCD-swizzled 1D grid: 9 q-tiles x 128 bh)
  attn128<<<dim3(1152), 256, 0, stream>>>(Qhp, Khp, VThp, xattn);
  // 5. output projection + bias -> d_out (fp32)
  gemm_out<<<dim3(520), 256, 0, stream>>>(xattn, wtout, (float*)d_out, b_out);
}